// Round 8
// baseline (1632.274 us; speedup 1.0000x reference)
//
#include <hip/hip_runtime.h>
#include <math.h>

#define NN 20000
#define NE 200000
#define NZ 10
#define NF 64
#define NWIN 400
#define NIN 320
#define NOUT 1604
#define CB 8    // edges per batch in conv_node

// ---------- workspace layout (bytes) ----------
#define OFF_TYPES   ((size_t)0)
#define OFF_SH      ((size_t)81920)
#define OFF_EF      (OFF_SH + (size_t)NE*16*4)
#define OFF_HS      (OFF_EF + (size_t)NE*8*4)
#define OFF_A       (OFF_HS + (size_t)NN*64*4)          // 24,401,920
#define A_BYTES     ((size_t)NN*1024*4)                 // 81,920,000
#define OFF_S0      (OFF_A + A_BYTES)
#define OFF_NODEB   (OFF_S0 + (size_t)NN*64*4)          // bf16 node [NN][320]
#define OFF_CNT     (OFF_NODEB + (size_t)NN*NIN*2)
#define OFF_OFFS    (OFF_CNT + (size_t)NN*4)
#define OFF_ELIST   (OFF_OFFS + (size_t)(NN+1)*4 + 12)
// post-node_mix1 aliases inside the (dead) A region:
#define OFF_HB      OFF_A                               // bf16 H [NN][416]
#define OFF_HSC     (OFF_A + (size_t)20000000)          // fp32 Hs [NN][100]
#define OFF_WD1T    (OFF_A + (size_t)30000000)          // bf16 [400][320]
#define OFF_WD2T    (OFF_A + (size_t)31000000)          // bf16 [1600][416]
#define OFF_WS1T    (OFF_A + (size_t)33000000)          // bf16 [100][320]

typedef __attribute__((ext_vector_type(8))) short bf16x8;
typedef __attribute__((ext_vector_type(8))) unsigned short u16x8;
typedef __attribute__((ext_vector_type(4))) float f32x4;

__device__ __forceinline__ void wave_sync() {
    __asm__ volatile("" ::: "memory");
    __builtin_amdgcn_wave_barrier();
    __asm__ volatile("" ::: "memory");
}
__device__ __forceinline__ float silu_f(float x)  { return x / (1.0f + __expf(-x)); }
__device__ __forceinline__ float sigm_f(float x)  { return 1.0f / (1.0f + __expf(-x)); }
__device__ __forceinline__ unsigned short f2bf(float v) {
    unsigned int u = __float_as_uint(v);
    unsigned int r = (u + 0x7fffu + ((u >> 16) & 1u)) >> 16;
    return (unsigned short)r;
}

// ---------------- types (one-hot -> int) ----------------
__global__ __launch_bounds__(256) void types_kernel(const float* __restrict__ x, int* __restrict__ types) {
    int n = blockIdx.x * 256 + threadIdx.x;
    if (n >= NN) return;
    int t = 0;
    #pragma unroll
    for (int z = 0; z < NZ; ++z) if (x[n*NZ + z] != 0.0f) t = z;
    types[n] = t;
}

// ---------------- edge geometry: sph(16) + radial basis(8) ----------------
__global__ __launch_bounds__(256) void edge_geom(const float* __restrict__ pos, const float* __restrict__ shifts,
                                                 const int* __restrict__ ei, float* __restrict__ sh, float* __restrict__ ef) {
    int e = blockIdx.x * 256 + threadIdx.x;
    if (e >= NE) return;
    int s = ei[e], rv = ei[NE + e];
    float vx = pos[rv*3+0] - pos[s*3+0] + shifts[e*3+0];
    float vy = pos[rv*3+1] - pos[s*3+1] + shifts[e*3+1];
    float vz = pos[rv*3+2] - pos[s*3+2] + shifts[e*3+2];
    float r = sqrtf(vx*vx + vy*vy + vz*vz) + 1e-9f;
    float inv = 1.0f / r;
    float x = vx*inv, y = vy*inv, z = vz*inv;

    const float s3  = 1.7320508075688772f;
    const float s15 = 3.872983346207417f;
    const float s5  = 2.23606797749979f;
    const float s358 = 2.0916500663351889f;
    const float s105 = 10.246950765959598f;
    const float s218 = 1.6201851746019651f;
    const float s7  = 2.6457513110645907f;
    float o[16];
    o[0] = 1.0f;
    o[1] = s3*x; o[2] = s3*y; o[3] = s3*z;
    o[4] = s15*x*y; o[5] = s15*y*z; o[6] = 0.5f*s5*(3.0f*z*z - 1.0f);
    o[7] = s15*x*z; o[8] = 0.5f*s15*(x*x - y*y);
    o[9]  = s358*y*(3.0f*x*x - y*y);
    o[10] = s105*x*y*z;
    o[11] = s218*y*(5.0f*z*z - 1.0f);
    o[12] = 0.5f*s7*(5.0f*z*z*z - 3.0f*z);
    o[13] = s218*x*(5.0f*z*z - 1.0f);
    o[14] = 0.5f*s105*(x*x - y*y)*z;
    o[15] = s358*x*(x*x - 3.0f*y*y);
    #pragma unroll
    for (int i = 0; i < 16; ++i) sh[e*16 + i] = o[i];

    float t = r * 0.2f;
    float env = 0.0f;
    if (t < 1.0f) {
        float t2 = t*t, t4 = t2*t2, t5 = t4*t;
        env = 1.0f - 21.0f*t5 + 35.0f*t5*t - 15.0f*t5*t2;
    }
    float c0 = 0.6324555320336759f;
    float a = 0.6283185307179586f * r;
    #pragma unroll
    for (int k = 0; k < 8; ++k)
        ef[e*8 + k] = c0 * sinf((float)(k+1) * a) * inv * env;
}

// ---------------- edge bucketing by receiver ----------------
__global__ __launch_bounds__(256) void deg_kernel(const float* __restrict__ ef, const int* __restrict__ ei,
                                                  int* __restrict__ cnt) {
    int e = blockIdx.x * 256 + threadIdx.x;
    if (e >= NE) return;
    if (ef[e*8] != 0.0f) atomicAdd(&cnt[ei[NE + e]], 1);
}

__global__ __launch_bounds__(1024) void scan_kernel(const int* __restrict__ cnt, int* __restrict__ offs) {
    __shared__ int part[1024];
    int t = threadIdx.x;
    int loc[20]; int s = 0;
    #pragma unroll
    for (int i = 0; i < 20; ++i) { int idx = t*20 + i; int c = (idx < NN) ? cnt[idx] : 0; loc[i] = s; s += c; }
    part[t] = s; __syncthreads();
    for (int d = 1; d < 1024; d <<= 1) {
        int v = 0; if (t >= d) v = part[t-d];
        __syncthreads();
        if (t >= d) part[t] += v;
        __syncthreads();
    }
    int pre = (t == 0) ? 0 : part[t-1];
    #pragma unroll
    for (int i = 0; i < 20; ++i) { int idx = t*20 + i; if (idx < NN) offs[idx] = pre + loc[i]; }
    if (t == 1023) offs[NN] = part[1023];
}

__global__ __launch_bounds__(256) void fill_kernel(const float* __restrict__ ef, const int* __restrict__ ei,
                                                   const int* __restrict__ offs, int* __restrict__ cur,
                                                   int* __restrict__ elist) {
    int e = blockIdx.x * 256 + threadIdx.x;
    if (e >= NE) return;
    if (ef[e*8] != 0.0f) {
        int r = ei[NE + e];
        int slot = offs[r] + atomicAdd(&cur[r], 1);
        elist[slot] = e;
    }
}

// ---------------- hs = hs_in @ W_up  (wave per node) ----------------
__global__ __launch_bounds__(256) void hs_kernel(const float* __restrict__ Wemb, const int* __restrict__ types,
                                                 const float* __restrict__ s0, const float* __restrict__ Wup,
                                                 float* __restrict__ hs, int mode) {
    int wid = threadIdx.x >> 6, lane = threadIdx.x & 63;
    int n = blockIdx.x * 4 + wid;
    if (n >= NN) return;
    __shared__ float sIn[4][64];
    if (mode == 0) { int t = types[n]; sIn[wid][lane] = Wemb[t*64 + lane]; }
    else           { sIn[wid][lane] = s0[n*64 + lane]; }
    wave_sync();
    float acc = 0.0f;
    #pragma unroll 8
    for (int g = 0; g < 64; ++g) acc += sIn[wid][g] * Wup[g*64 + lane];
    hs[n*64 + lane] = acc;
}

// ---------------- per-receiver conv, batched edge MLP ----------------
// One wave per node n; edges in batches of CB=8. sH1/sH2 laid out [CB][64]:
// writes are stride-1 (conflict-free), reads are uniform-address float4
// broadcasts. Accumulate loop fully unrolled with wave-uniform guard so the
// W[CB] register array is statically indexed (no scratch spill, rule #20).
__global__ __launch_bounds__(256) void conv_node(const float* __restrict__ ef, const float* __restrict__ sh,
                                                 const int* __restrict__ ei, const int* __restrict__ elist,
                                                 const int* __restrict__ offs, const float* __restrict__ hs,
                                                 const float* __restrict__ w1, const float* __restrict__ w2,
                                                 const float* __restrict__ w3, float* __restrict__ A) {
    int wid = threadIdx.x >> 6, lane = threadIdx.x & 63;
    int n = blockIdx.x * 4 + wid;
    if (n >= NN) return;
    __shared__ int sE[4][CB], sSND[4][CB];
    __shared__ __align__(16) float sEF[4][CB][8];
    __shared__ __align__(16) float sSH[4][CB][16];
    __shared__ __align__(16) float sH1[4][CB][64];
    __shared__ __align__(16) float sH2[4][CB][64];

    float w1c[8];
    #pragma unroll
    for (int k = 0; k < 8; ++k) w1c[k] = w1[k*64 + lane];

    float acc[16];
    #pragma unroll
    for (int m = 0; m < 16; ++m) acc[m] = 0.0f;

    int e0 = offs[n], e1 = offs[n+1];
    const float4* w3v = (const float4*)w3;

    for (int base = e0; base < e1; base += CB) {
        int ne = min(CB, e1 - base);   // wave-uniform

        if (lane < ne) {
            int e = elist[base + lane];
            sE[wid][lane] = e; sSND[wid][lane] = ei[e];
        }
        wave_sync();
        {   // stage ef: CB*8 = 64 slots (zero-padded)
            int el = lane >> 3, k = lane & 7;
            float v = 0.0f; if (el < ne) v = ef[(size_t)sE[wid][el]*8 + k];
            sEF[wid][el][k] = v;
        }
        #pragma unroll
        for (int p = 0; p < 2; ++p) {   // stage sh: CB*16 = 128 slots (zero-padded)
            int i = p*64 + lane; int el = i >> 4, m = i & 15;
            float v = 0.0f; if (el < ne) v = sh[(size_t)sE[wid][el]*16 + m] * 0.1f;
            sSH[wid][el][m] = v;
        }
        wave_sync();

        // h1[e][j]: lane = hidden unit j; ef read as uniform broadcast
        #pragma unroll
        for (int e = 0; e < CB; ++e) {
            const float4* efp = (const float4*)&sEF[wid][e][0];
            float4 a = efp[0], b = efp[1];
            float s = a.x*w1c[0] + a.y*w1c[1] + a.z*w1c[2] + a.w*w1c[3]
                    + b.x*w1c[4] + b.y*w1c[5] + b.z*w1c[6] + b.w*w1c[7];
            sH1[wid][e][lane] = silu_f(s);   // stride-1 store, conflict-free
        }
        wave_sync();

        // h2[e][lane] = silu(sum_j h1[e][j]*w2[j][lane]); w2 amortized over e
        float hv[CB];
        #pragma unroll
        for (int e = 0; e < CB; ++e) hv[e] = 0.0f;
        for (int j4 = 0; j4 < 16; ++j4) {
            float w20 = w2[(j4*4+0)*64 + lane];
            float w21 = w2[(j4*4+1)*64 + lane];
            float w22 = w2[(j4*4+2)*64 + lane];
            float w23 = w2[(j4*4+3)*64 + lane];
            #pragma unroll
            for (int e = 0; e < CB; ++e) {
                float4 hq = *(const float4*)&sH1[wid][e][j4*4];   // broadcast
                hv[e] += hq.x*w20 + hq.y*w21 + hq.z*w22 + hq.w*w23;
            }
        }
        #pragma unroll
        for (int e = 0; e < CB; ++e) sH2[wid][e][lane] = silu_f(hv[e]);
        wave_sync();

        // W[e] (4 l-channels of feature f=lane): w3 amortized over e
        float4 W[CB];
        #pragma unroll
        for (int e = 0; e < CB; ++e) { W[e].x = 0.f; W[e].y = 0.f; W[e].z = 0.f; W[e].w = 0.f; }
        for (int j4 = 0; j4 < 16; ++j4) {
            float4 r0 = w3v[(j4*4+0)*64 + lane];
            float4 r1 = w3v[(j4*4+1)*64 + lane];
            float4 r2 = w3v[(j4*4+2)*64 + lane];
            float4 r3 = w3v[(j4*4+3)*64 + lane];
            #pragma unroll
            for (int e = 0; e < CB; ++e) {
                float4 hq = *(const float4*)&sH2[wid][e][j4*4];   // broadcast
                W[e].x += hq.x*r0.x + hq.y*r1.x + hq.z*r2.x + hq.w*r3.x;
                W[e].y += hq.x*r0.y + hq.y*r1.y + hq.z*r2.y + hq.w*r3.y;
                W[e].z += hq.x*r0.z + hq.y*r1.z + hq.z*r2.z + hq.w*r3.z;
                W[e].w += hq.x*r0.w + hq.y*r1.w + hq.z*r2.w + hq.w*r3.w;
            }
        }

        // accumulate: fully unrolled, static W[i] indices, wave-uniform guard
        #pragma unroll
        for (int i = 0; i < CB; ++i) {
            if (i < ne) {
                float hsv = hs[(size_t)sSND[wid][i]*64 + lane];
                float wlx = W[i].x*hsv, wly = W[i].y*hsv, wlz = W[i].z*hsv, wlw = W[i].w*hsv;
                const float4* shp = (const float4*)&sSH[wid][i][0];
                float4 s0 = shp[0], s1 = shp[1], s2 = shp[2], s3 = shp[3];
                acc[0]  += s0.x*wlx;
                acc[1]  += s0.y*wly; acc[2]  += s0.z*wly; acc[3]  += s0.w*wly;
                acc[4]  += s1.x*wlz; acc[5]  += s1.y*wlz; acc[6]  += s1.z*wlz; acc[7]  += s1.w*wlz; acc[8] += s2.x*wlz;
                acc[9]  += s2.y*wlw; acc[10] += s2.z*wlw; acc[11] += s2.w*wlw;
                acc[12] += s3.x*wlw; acc[13] += s3.y*wlw; acc[14] += s3.z*wlw; acc[15] += s3.w*wlw;
            }
        }
        wave_sync();   // staging buffers reusable next batch
    }

    float* dst = A + (size_t)n * 1024;
    #pragma unroll
    for (int m = 0; m < 16; ++m) dst[m*64 + lane] = acc[m];
}

// ---------------- node mix, layer 0 (A layout [n][m][g]) ----------------
__global__ __launch_bounds__(256, 6) void node_mix0(const float* __restrict__ A, const int* __restrict__ types,
                                                 const float* __restrict__ Wm, const float* __restrict__ Wp_s,
                                                 const float* __restrict__ Wp_s2, const float* __restrict__ Wp_v,
                                                 const float* __restrict__ Wr_sg, const float* __restrict__ Wr_s2,
                                                 const float* __restrict__ Wr_v, const float* __restrict__ Wr_v2,
                                                 float* __restrict__ s0, unsigned short* __restrict__ node_b) {
    int wid = threadIdx.x >> 6, lane = threadIdx.x & 63;
    int n = blockIdx.x * 4 + wid;
    if (n >= NN) return;
    __shared__ __align__(16) float smem[4][1024];
    float* base = &smem[wid][0];

    // stage A row (coalesced, vectorized)
    {
        const float4* An = (const float4*)(A + (size_t)n * 1024);
        float4* sA4 = (float4*)base;
        #pragma unroll
        for (int it = 0; it < 4; ++it) sA4[it*64 + lane] = An[it*64 + lane];
    }

    float acc[16];
    #pragma unroll
    for (int m = 0; m < 16; ++m) acc[m] = 0.0f;
    const float4* A4 = (const float4*)base;
    for (int g4 = 0; g4 < 16; ++g4) {
        int g0 = g4*4;
        float wr1[4], wr2[4], wr3[4], wr0[4];
        #pragma unroll
        for (int gl = 0; gl < 4; ++gl) {
            wr0[gl] = Wm[(g0+gl)*64 + lane];
            wr1[gl] = Wm[4096 + (g0+gl)*64 + lane];
            wr2[gl] = Wm[8192 + (g0+gl)*64 + lane];
            wr3[gl] = Wm[12288 + (g0+gl)*64 + lane];
        }
        #pragma unroll
        for (int m = 0; m < 16; ++m) {
            float4 aq = A4[m*16 + g4];
            const float* wl = (m == 0) ? wr0 : (m < 4) ? wr1 : (m < 9) ? wr2 : wr3;
            acc[m] += aq.x*wl[0] + aq.y*wl[1] + aq.z*wl[2] + aq.w*wl[3];
        }
    }
    float Sv = 0.0f;
    #pragma unroll
    for (int m = 0; m < 16; ++m) Sv += acc[m]*acc[m];

    // wave-private alias of the (now-consumed) sA slice
    float* sPk0 = base + 0;
    float* sPk1 = base + 64;
    float* sPk2 = base + 128;
    float* sPk3 = base + 192;
    float* sSq  = base + 256;
    float* sPs  = base + 320;
    float* sPv0 = base + 384;
    float* sPv1 = base + 448;
    float* sPv2 = base + 512;
    float* sU   = base + 576;
    float* sVa0 = base + 640;
    float* sVa1 = base + 704;
    float* sVa2 = base + 768;

    sPk0[lane] = acc[0]; sPk1[lane] = acc[1];
    sPk2[lane] = acc[2]; sPk3[lane] = acc[3];
    sSq[lane] = Sv;

    int t = types[n];
    const float* Bs  = Wp_s  + t*4096;
    const float* Bs2 = Wp_s2 + t*4096;
    const float* Bv  = Wp_v  + t*4096;
    float ps = 0.f, pv0 = 0.f, pv1 = 0.f, pv2 = 0.f;
    #pragma unroll 4
    for (int g = 0; g < 64; ++g) {
        float pk0 = sPk0[g], pk1 = sPk1[g], pk2 = sPk2[g], pk3 = sPk3[g];
        float Sg = sSq[g];
        ps += Bs[g*64 + lane]*pk0 + Bs2[g*64 + lane]*Sg;
        float wv = Bv[g*64 + lane];
        pv0 += wv*pk1; pv1 += wv*pk2; pv2 += wv*pk3;
    }
    sPs[lane] = ps;
    sPv0[lane] = pv0; sPv1[lane] = pv1; sPv2[lane] = pv2;

    float sgl = 0.f, sgh = 0.f;
    #pragma unroll 8
    for (int g = 0; g < 64; ++g) {
        float pg = sPs[g];
        sgl += pg * Wr_sg[g*128 + lane];
        sgh += pg * Wr_sg[g*128 + 64 + lane];
    }
    float u = silu_f(sgl), sg_ = sigm_f(sgh);
    sU[lane] = u;

    float s0v = 0.f, va0 = 0.f, va1 = 0.f, va2 = 0.f;
    #pragma unroll 4
    for (int g = 0; g < 64; ++g) {
        s0v += sU[g] * Wr_s2[g*64 + lane];
        float wv = Wr_v[g*64 + lane];
        va0 += sPv0[g]*wv; va1 += sPv1[g]*wv; va2 += sPv2[g]*wv;
    }
    va0 *= sg_; va1 *= sg_; va2 *= sg_;
    sVa0[lane] = va0; sVa1[lane] = va1; sVa2[lane] = va2;

    float vb0 = 0.f, vb1 = 0.f, vb2 = 0.f;
    #pragma unroll 4
    for (int g = 0; g < 64; ++g) {
        float wv = Wr_v2[g*64 + lane];
        vb0 += sVa0[g]*wv; vb1 += sVa1[g]*wv; vb2 += sVa2[g]*wv;
    }
    s0[n*64 + lane] = s0v;
    unsigned short* nd = node_b + (size_t)n * NIN;
    nd[lane] = f2bf(s0v);
    nd[64 + lane*3+0] = f2bf(vb0); nd[64 + lane*3+1] = f2bf(vb1); nd[64 + lane*3+2] = f2bf(vb2);
}

// ---------------- node mix, layer 1 (A layout [n][m][g]) ----------------
__global__ __launch_bounds__(256, 6) void node_mix1(const float* __restrict__ A, const int* __restrict__ types,
                                                 const float* __restrict__ Wm, const float* __restrict__ Wp_s,
                                                 const float* __restrict__ Wp_s2, const float* __restrict__ Wsc,
                                                 const float* __restrict__ Wr1, const float* __restrict__ Wr2,
                                                 const float* __restrict__ s0, unsigned short* __restrict__ node_b) {
    int wid = threadIdx.x >> 6, lane = threadIdx.x & 63;
    int n = blockIdx.x * 4 + wid;
    if (n >= NN) return;
    __shared__ __align__(16) float smem[4][1024];
    float* base = &smem[wid][0];

    float s0in = s0[n*64 + lane];

    {
        const float4* An = (const float4*)(A + (size_t)n * 1024);
        float4* sA4 = (float4*)base;
        #pragma unroll
        for (int it = 0; it < 4; ++it) sA4[it*64 + lane] = An[it*64 + lane];
    }

    float acc[16];
    #pragma unroll
    for (int m = 0; m < 16; ++m) acc[m] = 0.0f;
    const float4* A4 = (const float4*)base;
    for (int g4 = 0; g4 < 16; ++g4) {
        int g0 = g4*4;
        float wr1[4], wr2[4], wr3[4], wr0[4];
        #pragma unroll
        for (int gl = 0; gl < 4; ++gl) {
            wr0[gl] = Wm[(g0+gl)*64 + lane];
            wr1[gl] = Wm[4096 + (g0+gl)*64 + lane];
            wr2[gl] = Wm[8192 + (g0+gl)*64 + lane];
            wr3[gl] = Wm[12288 + (g0+gl)*64 + lane];
        }
        #pragma unroll
        for (int m = 0; m < 16; ++m) {
            float4 aq = A4[m*16 + g4];
            const float* wl = (m == 0) ? wr0 : (m < 4) ? wr1 : (m < 9) ? wr2 : wr3;
            acc[m] += aq.x*wl[0] + aq.y*wl[1] + aq.z*wl[2] + aq.w*wl[3];
        }
    }
    float Sv = 0.0f;
    #pragma unroll
    for (int m = 0; m < 16; ++m) Sv += acc[m]*acc[m];

    float* sC  = base + 0;
    float* sSq = base + 64;
    float* sS0 = base + 128;
    float* sP  = base + 192;
    float* sU  = base + 256;

    sC[lane] = acc[0];
    sSq[lane] = Sv;
    sS0[lane] = s0in;

    int t = types[n];
    const float* Bs  = Wp_s  + t*4096;
    const float* Bs2 = Wp_s2 + t*4096;
    const float* Bsc = Wsc   + t*4096;
    float p = 0.f;
    #pragma unroll 4
    for (int g = 0; g < 64; ++g)
        p += Bs[g*64 + lane]*sC[g] + Bs2[g*64 + lane]*sSq[g] + Bsc[g*64 + lane]*sS0[g];
    sP[lane] = p;

    float uq = 0.f;
    #pragma unroll 8
    for (int g = 0; g < 64; ++g) uq += sP[g] * Wr1[g*64 + lane];
    sU[lane] = silu_f(uq);

    float hv = 0.f;
    #pragma unroll 8
    for (int g = 0; g < 64; ++g) hv += sU[g] * Wr2[g*64 + lane];
    node_b[(size_t)n*NIN + 256 + lane] = f2bf(hv);
}

// ---------------- weight transpose + bf16 convert: W[K][N] -> Wt[N][Kpad] ----------------
__global__ __launch_bounds__(256) void wtrans_kernel(const float* __restrict__ W, unsigned short* __restrict__ Wt,
                                                     int Kreal, int Nreal, int Kpad) {
    int idx = blockIdx.x * 256 + threadIdx.x;
    int total = Nreal * Kpad;
    if (idx >= total) return;
    int n = idx / Kpad, k = idx - n*Kpad;
    float v = (k < Kreal) ? W[(size_t)k*Nreal + n] : 0.0f;
    Wt[idx] = f2bf(v);
}

// ---------------- bf16 MFMA GEMM: C = act(A@Bt^T + bias) ----------------
template<int ACT, int BF16OUT>
__global__ __launch_bounds__(256) void gemm_mfma(const unsigned short* __restrict__ Ag, int lda,
                                                 const unsigned short* __restrict__ Bt, int ldb,
                                                 const float* __restrict__ bias, const float* __restrict__ alpha_p,
                                                 void* __restrict__ Cout, int ldc,
                                                 int M, int Nreal, int Nstore, int Kpad) {
    __shared__ __align__(16) unsigned short As[128*40];  // +8 pad
    __shared__ __align__(16) unsigned short Bs[128*40];
    const int tid = threadIdx.x;
    const int bm = blockIdx.y * 128, bn = blockIdx.x * 128;
    const int r = tid >> 1, koff = (tid & 1) * 16;
    const int wave = tid >> 6, lane = tid & 63;
    const int wm = (wave >> 1) * 64, wn = (wave & 1) * 64;
    const int q = lane >> 4, m15 = lane & 15;

    f32x4 acc[4][4];
    #pragma unroll
    for (int i = 0; i < 4; ++i)
        #pragma unroll
        for (int j = 0; j < 4; ++j) acc[i][j] = (f32x4){0.f, 0.f, 0.f, 0.f};

    const bool aok = (bm + r) < M;
    const bool bok = (bn + r) < Nreal;
    const size_t abase = (size_t)(bm + r) * lda + koff;
    const size_t bbase = (size_t)(bn + r) * ldb + koff;

    for (int k0 = 0; k0 < Kpad; k0 += 32) {
        u16x8 av0 = {0,0,0,0,0,0,0,0}, av1 = {0,0,0,0,0,0,0,0};
        u16x8 bv0 = {0,0,0,0,0,0,0,0}, bv1 = {0,0,0,0,0,0,0,0};
        if (aok) { av0 = *(const u16x8*)(Ag + abase + k0); av1 = *(const u16x8*)(Ag + abase + k0 + 8); }
        if (bok) { bv0 = *(const u16x8*)(Bt + bbase + k0); bv1 = *(const u16x8*)(Bt + bbase + k0 + 8); }
        *(u16x8*)&As[r*40 + koff]     = av0;
        *(u16x8*)&As[r*40 + koff + 8] = av1;
        *(u16x8*)&Bs[r*40 + koff]     = bv0;
        *(u16x8*)&Bs[r*40 + koff + 8] = bv1;
        __syncthreads();

        bf16x8 af[4], bfr[4];
        #pragma unroll
        for (int mi = 0; mi < 4; ++mi) af[mi]  = *(const bf16x8*)&As[(wm + mi*16 + m15)*40 + q*8];
        #pragma unroll
        for (int ni = 0; ni < 4; ++ni) bfr[ni] = *(const bf16x8*)&Bs[(wn + ni*16 + m15)*40 + q*8];
        #pragma unroll
        for (int mi = 0; mi < 4; ++mi)
            #pragma unroll
            for (int ni = 0; ni < 4; ++ni)
                acc[mi][ni] = __builtin_amdgcn_mfma_f32_16x16x32_bf16(af[mi], bfr[ni], acc[mi][ni], 0, 0, 0);
        __syncthreads();
    }

    float alpha = (ACT == 1) ? *alpha_p : 0.0f;
    #pragma unroll
    for (int mi = 0; mi < 4; ++mi) {
        int row0 = bm + wm + mi*16 + q*4;
        #pragma unroll
        for (int ni = 0; ni < 4; ++ni) {
            int col = bn + wn + ni*16 + m15;
            #pragma unroll
            for (int rg = 0; rg < 4; ++rg) {
                int row = row0 + rg;
                if (row >= M) continue;
                if (BF16OUT) {
                    if (col >= Nstore) continue;
                    float v = 0.0f;
                    if (col < Nreal) {
                        v = acc[mi][ni][rg] + bias[col];
                        v = (v >= 0.0f) ? v : alpha*v;
                    }
                    ((unsigned short*)Cout)[(size_t)row*ldc + col] = f2bf(v);
                } else {
                    if (col >= Nreal) continue;
                    float v = acc[mi][ni][rg] + bias[col];
                    if (ACT == 1) v = (v >= 0.0f) ? v : alpha*v;
                    else          v = 0.5f * (tanhf(v) + 1.0f);
                    ((float*)Cout)[(size_t)row*ldc + col] = v;
                }
            }
        }
    }
}

// ---------------- scal head ----------------
__global__ __launch_bounds__(256) void scal_kernel(const float* __restrict__ Hs, const float* __restrict__ Ws2,
                                                   const float* __restrict__ bs2, const float* __restrict__ spd,
                                                   float* __restrict__ out) {
    int idx = blockIdx.x * 256 + threadIdx.x;
    int n = idx >> 2, c = idx & 3;
    if (n >= NN) return;
    float acc = bs2[c];
    const float* hr = Hs + (size_t)n * 100;
    #pragma unroll 10
    for (int k = 0; k < 100; ++k) acc += hr[k] * Ws2[k*4 + c];
    acc = fmaxf(acc, 0.0f) * spd[n*4 + c];
    out[(size_t)n*NOUT + 1600 + c] = acc;
}

extern "C" void kernel_launch(void* const* d_in, const int* in_sizes, int n_in,
                              void* d_out, int out_size, void* d_ws, size_t ws_size,
                              hipStream_t stream) {
    const float* x      = (const float*)d_in[0];
    const float* pos    = (const float*)d_in[1];
    const float* shifts = (const float*)d_in[2];
    const float* spd    = (const float*)d_in[3];
    const int*   ei     = (const int*)  d_in[4];
    const float* W_embed= (const float*)d_in[5];
    const float* W_up0  = (const float*)d_in[6];
    const float* r0_w1  = (const float*)d_in[7];
    const float* r0_w2  = (const float*)d_in[9];
    const float* r0_w3  = (const float*)d_in[11];
    const float* Wm0    = (const float*)d_in[12];
    const float* Wp0_s  = (const float*)d_in[13];
    const float* Wp0_s2 = (const float*)d_in[14];
    const float* Wp0_v  = (const float*)d_in[15];
    const float* Wr0_sg = (const float*)d_in[16];
    const float* Wr0_v  = (const float*)d_in[17];
    const float* Wr0_s2 = (const float*)d_in[18];
    const float* Wr0_v2 = (const float*)d_in[19];
    const float* W_up1  = (const float*)d_in[20];
    const float* r1_w1  = (const float*)d_in[21];
    const float* r1_w2  = (const float*)d_in[23];
    const float* r1_w3  = (const float*)d_in[25];
    const float* Wm1    = (const float*)d_in[26];
    const float* Wsc1   = (const float*)d_in[27];
    const float* Wp1_s  = (const float*)d_in[28];
    const float* Wp1_s2 = (const float*)d_in[29];
    const float* Wr1_1  = (const float*)d_in[30];
    const float* Wr1_2  = (const float*)d_in[31];
    const float* Wd1    = (const float*)d_in[32];
    const float* bd1    = (const float*)d_in[33];
    const float* a_d    = (const float*)d_in[34];
    const float* Wd2    = (const float*)d_in[35];
    const float* bd2    = (const float*)d_in[36];
    const float* Ws1    = (const float*)d_in[37];
    const float* bs1    = (const float*)d_in[38];
    const float* a_s    = (const float*)d_in[39];
    const float* Ws2    = (const float*)d_in[40];
    const float* bs2    = (const float*)d_in[41];
    float* out = (float*)d_out;

    char* w = (char*)d_ws;
    int*   types = (int*)  (w + OFF_TYPES);
    float* sh    = (float*)(w + OFF_SH);
    float* ef    = (float*)(w + OFF_EF);
    float* hs    = (float*)(w + OFF_HS);
    float* A     = (float*)(w + OFF_A);
    float* s0    = (float*)(w + OFF_S0);
    unsigned short* node_b = (unsigned short*)(w + OFF_NODEB);
    int*   cnt   = (int*)  (w + OFF_CNT);
    int*   offs  = (int*)  (w + OFF_OFFS);
    int*   elist = (int*)  (w + OFF_ELIST);
    unsigned short* H_b   = (unsigned short*)(w + OFF_HB);
    float*          Hs    = (float*)(w + OFF_HSC);
    unsigned short* Wd1t  = (unsigned short*)(w + OFF_WD1T);
    unsigned short* Wd2t  = (unsigned short*)(w + OFF_WD2T);
    unsigned short* Ws1t  = (unsigned short*)(w + OFF_WS1T);

    types_kernel<<<(NN + 255)/256, 256, 0, stream>>>(x, types);
    edge_geom<<<(NE + 255)/256, 256, 0, stream>>>(pos, shifts, ei, sh, ef);

    hipMemsetAsync(cnt, 0, (size_t)NN*4, stream);
    deg_kernel<<<(NE + 255)/256, 256, 0, stream>>>(ef, ei, cnt);
    scan_kernel<<<1, 1024, 0, stream>>>(cnt, offs);
    hipMemsetAsync(cnt, 0, (size_t)NN*4, stream);
    fill_kernel<<<(NE + 255)/256, 256, 0, stream>>>(ef, ei, offs, cnt, elist);

    hs_kernel<<<NN/4, 256, 0, stream>>>(W_embed, types, nullptr, W_up0, hs, 0);
    conv_node<<<NN/4, 256, 0, stream>>>(ef, sh, ei, elist, offs, hs, r0_w1, r0_w2, r0_w3, A);
    node_mix0<<<NN/4, 256, 0, stream>>>(A, types, Wm0, Wp0_s, Wp0_s2, Wp0_v, Wr0_sg, Wr0_s2, Wr0_v, Wr0_v2, s0, node_b);

    hs_kernel<<<NN/4, 256, 0, stream>>>(nullptr, nullptr, s0, W_up1, hs, 1);
    conv_node<<<NN/4, 256, 0, stream>>>(ef, sh, ei, elist, offs, hs, r1_w1, r1_w2, r1_w3, A);
    node_mix1<<<NN/4, 256, 0, stream>>>(A, types, Wm1, Wp1_s, Wp1_s2, Wsc1, Wr1_1, Wr1_2, s0, node_b);

    // weight transposes into the now-dead A region
    wtrans_kernel<<<(400*320 + 255)/256, 256, 0, stream>>>(Wd1, Wd1t, 320, 400, 320);
    wtrans_kernel<<<(1600*416 + 255)/256, 256, 0, stream>>>(Wd2, Wd2t, 400, 1600, 416);
    wtrans_kernel<<<(100*320 + 255)/256, 256, 0, stream>>>(Ws1, Ws1t, 320, 100, 320);

    // readout: node_b @ Wd1 -> H_b (bf16, K padded to 416); H_b @ Wd2 -> out (tanh-dos)
    gemm_mfma<1,1><<<dim3(4, 157), 256, 0, stream>>>(node_b, NIN, Wd1t, 320, bd1, a_d, H_b, 416, NN, 400, 416, 320);
    gemm_mfma<2,0><<<dim3(13, 157), 256, 0, stream>>>(H_b, 416, Wd2t, 416, bd2, a_d, out, NOUT, NN, 1600, 1600, 416);
    gemm_mfma<1,0><<<dim3(1, 157), 256, 0, stream>>>(node_b, NIN, Ws1t, 320, bs1, a_s, Hs, 100, NN, 100, 100, 320);
    scal_kernel<<<(NN*4 + 255)/256, 256, 0, stream>>>(Hs, Ws2, bs2, spd, out);
}

// Round 9
// 913.538 us; speedup vs baseline: 1.7868x; 1.7868x over previous
//
#include <hip/hip_runtime.h>
#include <math.h>

#define NN 20000
#define NE 200000
#define NZ 10
#define NF 64
#define NWIN 400
#define NIN 320
#define NOUT 1604
#define GE 16   // edges per wave in edge_mlp

// ---------- workspace layout (bytes) ----------
#define OFF_TYPES   ((size_t)0)
#define OFF_SH      ((size_t)81920)
#define OFF_EF      (OFF_SH + (size_t)NE*16*4)
#define OFF_HS      (OFF_EF + (size_t)NE*8*4)
#define OFF_A       (OFF_HS + (size_t)NN*64*4)          // 24,401,920
#define A_BYTES     ((size_t)NN*1024*4)                 // 81,920,000 (now Wbuf: bf16x4 per lane, cap 160K edges)
#define OFF_S0      (OFF_A + A_BYTES)
#define OFF_NODEB   (OFF_S0 + (size_t)NN*64*4)          // bf16 node [NN][320]
#define OFF_CNT     (OFF_NODEB + (size_t)NN*NIN*2)
#define OFF_OFFS    (OFF_CNT + (size_t)NN*4)
#define OFF_ELIST   (OFF_OFFS + (size_t)(NN+1)*4 + 12)
// post-node_mix1 aliases inside the (dead) Wbuf/A region:
#define OFF_HB      OFF_A                               // bf16 H [NN][416]
#define OFF_HSC     (OFF_A + (size_t)20000000)          // fp32 Hs [NN][100]
#define OFF_WD1T    (OFF_A + (size_t)30000000)          // bf16 [400][320]
#define OFF_WD2T    (OFF_A + (size_t)31000000)          // bf16 [1600][416]
#define OFF_WS1T    (OFF_A + (size_t)33000000)          // bf16 [100][320]

typedef __attribute__((ext_vector_type(8))) short bf16x8;
typedef __attribute__((ext_vector_type(8))) unsigned short u16x8;
typedef __attribute__((ext_vector_type(4))) float f32x4;

__device__ __forceinline__ void wave_sync() {
    __asm__ volatile("" ::: "memory");
    __builtin_amdgcn_wave_barrier();
    __asm__ volatile("" ::: "memory");
}
__device__ __forceinline__ float silu_f(float x)  { return x / (1.0f + __expf(-x)); }
__device__ __forceinline__ float sigm_f(float x)  { return 1.0f / (1.0f + __expf(-x)); }
__device__ __forceinline__ unsigned short f2bf(float v) {
    unsigned int u = __float_as_uint(v);
    unsigned int r = (u + 0x7fffu + ((u >> 16) & 1u)) >> 16;
    return (unsigned short)r;
}
__device__ __forceinline__ float bf2f(unsigned short v) {
    return __uint_as_float(((unsigned int)v) << 16);
}

// ---------------- types (one-hot -> int) ----------------
__global__ __launch_bounds__(256) void types_kernel(const float* __restrict__ x, int* __restrict__ types) {
    int n = blockIdx.x * 256 + threadIdx.x;
    if (n >= NN) return;
    int t = 0;
    #pragma unroll
    for (int z = 0; z < NZ; ++z) if (x[n*NZ + z] != 0.0f) t = z;
    types[n] = t;
}

// ---------------- edge geometry: sph(16) + radial basis(8) ----------------
__global__ __launch_bounds__(256) void edge_geom(const float* __restrict__ pos, const float* __restrict__ shifts,
                                                 const int* __restrict__ ei, float* __restrict__ sh, float* __restrict__ ef) {
    int e = blockIdx.x * 256 + threadIdx.x;
    if (e >= NE) return;
    int s = ei[e], rv = ei[NE + e];
    float vx = pos[rv*3+0] - pos[s*3+0] + shifts[e*3+0];
    float vy = pos[rv*3+1] - pos[s*3+1] + shifts[e*3+1];
    float vz = pos[rv*3+2] - pos[s*3+2] + shifts[e*3+2];
    float r = sqrtf(vx*vx + vy*vy + vz*vz) + 1e-9f;
    float inv = 1.0f / r;
    float x = vx*inv, y = vy*inv, z = vz*inv;

    const float s3  = 1.7320508075688772f;
    const float s15 = 3.872983346207417f;
    const float s5  = 2.23606797749979f;
    const float s358 = 2.0916500663351889f;
    const float s105 = 10.246950765959598f;
    const float s218 = 1.6201851746019651f;
    const float s7  = 2.6457513110645907f;
    float o[16];
    o[0] = 1.0f;
    o[1] = s3*x; o[2] = s3*y; o[3] = s3*z;
    o[4] = s15*x*y; o[5] = s15*y*z; o[6] = 0.5f*s5*(3.0f*z*z - 1.0f);
    o[7] = s15*x*z; o[8] = 0.5f*s15*(x*x - y*y);
    o[9]  = s358*y*(3.0f*x*x - y*y);
    o[10] = s105*x*y*z;
    o[11] = s218*y*(5.0f*z*z - 1.0f);
    o[12] = 0.5f*s7*(5.0f*z*z*z - 3.0f*z);
    o[13] = s218*x*(5.0f*z*z - 1.0f);
    o[14] = 0.5f*s105*(x*x - y*y)*z;
    o[15] = s358*x*(x*x - 3.0f*y*y);
    #pragma unroll
    for (int i = 0; i < 16; ++i) sh[e*16 + i] = o[i];

    float t = r * 0.2f;
    float env = 0.0f;
    if (t < 1.0f) {
        float t2 = t*t, t4 = t2*t2, t5 = t4*t;
        env = 1.0f - 21.0f*t5 + 35.0f*t5*t - 15.0f*t5*t2;
    }
    float c0 = 0.6324555320336759f;
    float a = 0.6283185307179586f * r;
    #pragma unroll
    for (int k = 0; k < 8; ++k)
        ef[e*8 + k] = c0 * sinf((float)(k+1) * a) * inv * env;
}

// ---------------- edge bucketing by receiver ----------------
__global__ __launch_bounds__(256) void deg_kernel(const float* __restrict__ ef, const int* __restrict__ ei,
                                                  int* __restrict__ cnt) {
    int e = blockIdx.x * 256 + threadIdx.x;
    if (e >= NE) return;
    if (ef[e*8] != 0.0f) atomicAdd(&cnt[ei[NE + e]], 1);
}

__global__ __launch_bounds__(1024) void scan_kernel(const int* __restrict__ cnt, int* __restrict__ offs) {
    __shared__ int part[1024];
    int t = threadIdx.x;
    int loc[20]; int s = 0;
    #pragma unroll
    for (int i = 0; i < 20; ++i) { int idx = t*20 + i; int c = (idx < NN) ? cnt[idx] : 0; loc[i] = s; s += c; }
    part[t] = s; __syncthreads();
    for (int d = 1; d < 1024; d <<= 1) {
        int v = 0; if (t >= d) v = part[t-d];
        __syncthreads();
        if (t >= d) part[t] += v;
        __syncthreads();
    }
    int pre = (t == 0) ? 0 : part[t-1];
    #pragma unroll
    for (int i = 0; i < 20; ++i) { int idx = t*20 + i; if (idx < NN) offs[idx] = pre + loc[i]; }
    if (t == 1023) offs[NN] = part[1023];
}

__global__ __launch_bounds__(256) void fill_kernel(const float* __restrict__ ef, const int* __restrict__ ei,
                                                   const int* __restrict__ offs, int* __restrict__ cur,
                                                   int* __restrict__ elist) {
    int e = blockIdx.x * 256 + threadIdx.x;
    if (e >= NE) return;
    if (ef[e*8] != 0.0f) {
        int r = ei[NE + e];
        int slot = offs[r] + atomicAdd(&cur[r], 1);
        elist[slot] = e;
    }
}

// ---------------- hs = hs_in @ W_up  (wave per node) ----------------
__global__ __launch_bounds__(256) void hs_kernel(const float* __restrict__ Wemb, const int* __restrict__ types,
                                                 const float* __restrict__ s0, const float* __restrict__ Wup,
                                                 float* __restrict__ hs, int mode) {
    int wid = threadIdx.x >> 6, lane = threadIdx.x & 63;
    int n = blockIdx.x * 4 + wid;
    if (n >= NN) return;
    __shared__ float sIn[4][64];
    if (mode == 0) { int t = types[n]; sIn[wid][lane] = Wemb[t*64 + lane]; }
    else           { sIn[wid][lane] = s0[n*64 + lane]; }
    wave_sync();
    float acc = 0.0f;
    #pragma unroll 8
    for (int g = 0; g < 64; ++g) acc += sIn[wid][g] * Wup[g*64 + lane];
    hs[n*64 + lane] = acc;
}

// ---------------- edge MLP: wl[pos][lane] = (hid@w3)[lane] * hs[snd][lane] ----------------
// Wave per GE=16 compacted edges (good weight amortization, perfect load balance,
// no atomics). Output bf16x4 per lane (8B), coalesced 512B/edge, compacted by pos
// so the per-node gather reads contiguous rows. LDS [e][64] layout (conflict-free).
__global__ __launch_bounds__(256) void edge_mlp(const float* __restrict__ ef, const int* __restrict__ ei,
                                                const int* __restrict__ elist, const int* __restrict__ offs,
                                                const float* __restrict__ hs, const float* __restrict__ w1,
                                                const float* __restrict__ w2, const float* __restrict__ w3,
                                                ushort4* __restrict__ Wb) {
    int wid = threadIdx.x >> 6, lane = threadIdx.x & 63;
    int Ea = offs[NN];
    int base = (blockIdx.x * 4 + wid) * GE;
    if (base >= Ea) return;
    int ne = min(GE, Ea - base);

    __shared__ int sE[4][GE], sSND[4][GE];
    __shared__ __align__(16) float sEF[4][GE][8];
    __shared__ __align__(16) float sHH[4][GE][64];   // h1, then overwritten with h2

    if (lane < ne) {
        int e = elist[base + lane];
        sE[wid][lane] = e; sSND[wid][lane] = ei[e];
    }
    wave_sync();
    #pragma unroll
    for (int p = 0; p < 2; ++p) {   // stage ef: GE*8 = 128 slots (zero-padded)
        int i = p*64 + lane; int el = i >> 3, k = i & 7;
        float v = 0.0f; if (el < ne) v = ef[(size_t)sE[wid][el]*8 + k];
        sEF[wid][el][k] = v;
    }
    wave_sync();

    float w1c[8];
    #pragma unroll
    for (int k = 0; k < 8; ++k) w1c[k] = w1[k*64 + lane];

    // h1[e][lane]
    #pragma unroll
    for (int e = 0; e < GE; ++e) {
        const float4* efp = (const float4*)&sEF[wid][e][0];
        float4 a = efp[0], b = efp[1];
        float s = a.x*w1c[0] + a.y*w1c[1] + a.z*w1c[2] + a.w*w1c[3]
                + b.x*w1c[4] + b.y*w1c[5] + b.z*w1c[6] + b.w*w1c[7];
        sHH[wid][e][lane] = silu_f(s);
    }
    wave_sync();

    // h2[e] in registers: w2 loads amortized over GE edges
    float hv[GE];
    #pragma unroll
    for (int e = 0; e < GE; ++e) hv[e] = 0.0f;
    for (int j4 = 0; j4 < 16; ++j4) {
        float w20 = w2[(j4*4+0)*64 + lane];
        float w21 = w2[(j4*4+1)*64 + lane];
        float w22 = w2[(j4*4+2)*64 + lane];
        float w23 = w2[(j4*4+3)*64 + lane];
        #pragma unroll
        for (int e = 0; e < GE; ++e) {
            float4 hq = *(const float4*)&sHH[wid][e][j4*4];   // broadcast
            hv[e] += hq.x*w20 + hq.y*w21 + hq.z*w22 + hq.w*w23;
        }
    }
    wave_sync();
    #pragma unroll
    for (int e = 0; e < GE; ++e) sHH[wid][e][lane] = silu_f(hv[e]);   // reuse buffer
    wave_sync();

    // W[e]: w3 loads amortized over GE edges
    float4 W[GE];
    #pragma unroll
    for (int e = 0; e < GE; ++e) { W[e].x = 0.f; W[e].y = 0.f; W[e].z = 0.f; W[e].w = 0.f; }
    const float4* w3v = (const float4*)w3;
    for (int j4 = 0; j4 < 16; ++j4) {
        float4 r0 = w3v[(j4*4+0)*64 + lane];
        float4 r1 = w3v[(j4*4+1)*64 + lane];
        float4 r2 = w3v[(j4*4+2)*64 + lane];
        float4 r3 = w3v[(j4*4+3)*64 + lane];
        #pragma unroll
        for (int e = 0; e < GE; ++e) {
            float4 hq = *(const float4*)&sHH[wid][e][j4*4];   // broadcast
            W[e].x += hq.x*r0.x + hq.y*r1.x + hq.z*r2.x + hq.w*r3.x;
            W[e].y += hq.x*r0.y + hq.y*r1.y + hq.z*r2.y + hq.w*r3.y;
            W[e].z += hq.x*r0.z + hq.y*r1.z + hq.z*r2.z + hq.w*r3.z;
            W[e].w += hq.x*r0.w + hq.y*r1.w + hq.z*r2.w + hq.w*r3.w;
        }
    }

    // fold hs[snd] and store bf16x4 (static W index + wave-uniform guard)
    #pragma unroll
    for (int i = 0; i < GE; ++i) {
        if (i < ne) {
            float hsv = hs[(size_t)sSND[wid][i]*64 + lane];
            ushort4 o;
            o.x = f2bf(W[i].x * hsv);
            o.y = f2bf(W[i].y * hsv);
            o.z = f2bf(W[i].z * hsv);
            o.w = f2bf(W[i].w * hsv);
            Wb[(size_t)(base + i)*64 + lane] = o;
        }
    }
}

// ---------------- node mix, layer 0 — gather fused (A never hits HBM) ----------------
__global__ __launch_bounds__(256, 6) void node_mix0(const ushort4* __restrict__ Wb, const int* __restrict__ elist,
                                                 const int* __restrict__ offs, const float* __restrict__ sh,
                                                 const int* __restrict__ types,
                                                 const float* __restrict__ Wm, const float* __restrict__ Wp_s,
                                                 const float* __restrict__ Wp_s2, const float* __restrict__ Wp_v,
                                                 const float* __restrict__ Wr_sg, const float* __restrict__ Wr_s2,
                                                 const float* __restrict__ Wr_v, const float* __restrict__ Wr_v2,
                                                 float* __restrict__ s0, unsigned short* __restrict__ node_b) {
    int wid = threadIdx.x >> 6, lane = threadIdx.x & 63;
    int n = blockIdx.x * 4 + wid;
    if (n >= NN) return;
    __shared__ __align__(16) float smem[4][1024];
    float* base = &smem[wid][0];

    // gather prologue: A row built in registers from Wbuf + sh
    {
        float arow[16];
        #pragma unroll
        for (int m = 0; m < 16; ++m) arow[m] = 0.0f;
        int e0 = offs[n], e1 = offs[n+1];
        for (int pos = e0; pos < e1; ++pos) {
            int eid = __builtin_amdgcn_readfirstlane(elist[pos]);
            ushort4 wv = Wb[(size_t)pos*64 + lane];
            float wlx = bf2f(wv.x)*0.1f, wly = bf2f(wv.y)*0.1f;
            float wlz = bf2f(wv.z)*0.1f, wlw = bf2f(wv.w)*0.1f;
            const float4* shp = (const float4*)(sh + (size_t)eid*16);
            float4 sa = shp[0], sb = shp[1], sc = shp[2], sd = shp[3];   // uniform
            arow[0]  += sa.x*wlx;
            arow[1]  += sa.y*wly; arow[2]  += sa.z*wly; arow[3]  += sa.w*wly;
            arow[4]  += sb.x*wlz; arow[5]  += sb.y*wlz; arow[6]  += sb.z*wlz; arow[7] += sb.w*wlz; arow[8] += sc.x*wlz;
            arow[9]  += sc.y*wlw; arow[10] += sc.z*wlw; arow[11] += sc.w*wlw;
            arow[12] += sd.x*wlw; arow[13] += sd.y*wlw; arow[14] += sd.z*wlw; arow[15] += sd.w*wlw;
        }
        #pragma unroll
        for (int m = 0; m < 16; ++m) base[m*64 + lane] = arow[m];
    }

    float acc[16];
    #pragma unroll
    for (int m = 0; m < 16; ++m) acc[m] = 0.0f;
    const float4* A4 = (const float4*)base;
    for (int g4 = 0; g4 < 16; ++g4) {
        int g0 = g4*4;
        float wr1[4], wr2[4], wr3[4], wr0[4];
        #pragma unroll
        for (int gl = 0; gl < 4; ++gl) {
            wr0[gl] = Wm[(g0+gl)*64 + lane];
            wr1[gl] = Wm[4096 + (g0+gl)*64 + lane];
            wr2[gl] = Wm[8192 + (g0+gl)*64 + lane];
            wr3[gl] = Wm[12288 + (g0+gl)*64 + lane];
        }
        #pragma unroll
        for (int m = 0; m < 16; ++m) {
            float4 aq = A4[m*16 + g4];
            const float* wl = (m == 0) ? wr0 : (m < 4) ? wr1 : (m < 9) ? wr2 : wr3;
            acc[m] += aq.x*wl[0] + aq.y*wl[1] + aq.z*wl[2] + aq.w*wl[3];
        }
    }
    float Sv = 0.0f;
    #pragma unroll
    for (int m = 0; m < 16; ++m) Sv += acc[m]*acc[m];

    // wave-private alias of the (now-consumed) A slice
    float* sPk0 = base + 0;
    float* sPk1 = base + 64;
    float* sPk2 = base + 128;
    float* sPk3 = base + 192;
    float* sSq  = base + 256;
    float* sPs  = base + 320;
    float* sPv0 = base + 384;
    float* sPv1 = base + 448;
    float* sPv2 = base + 512;
    float* sU   = base + 576;
    float* sVa0 = base + 640;
    float* sVa1 = base + 704;
    float* sVa2 = base + 768;

    sPk0[lane] = acc[0]; sPk1[lane] = acc[1];
    sPk2[lane] = acc[2]; sPk3[lane] = acc[3];
    sSq[lane] = Sv;

    int t = types[n];
    const float* Bs  = Wp_s  + t*4096;
    const float* Bs2 = Wp_s2 + t*4096;
    const float* Bv  = Wp_v  + t*4096;
    float ps = 0.f, pv0 = 0.f, pv1 = 0.f, pv2 = 0.f;
    #pragma unroll 4
    for (int g = 0; g < 64; ++g) {
        float pk0 = sPk0[g], pk1 = sPk1[g], pk2 = sPk2[g], pk3 = sPk3[g];
        float Sg = sSq[g];
        ps += Bs[g*64 + lane]*pk0 + Bs2[g*64 + lane]*Sg;
        float wv = Bv[g*64 + lane];
        pv0 += wv*pk1; pv1 += wv*pk2; pv2 += wv*pk3;
    }
    sPs[lane] = ps;
    sPv0[lane] = pv0; sPv1[lane] = pv1; sPv2[lane] = pv2;

    float sgl = 0.f, sgh = 0.f;
    #pragma unroll 8
    for (int g = 0; g < 64; ++g) {
        float pg = sPs[g];
        sgl += pg * Wr_sg[g*128 + lane];
        sgh += pg * Wr_sg[g*128 + 64 + lane];
    }
    float u = silu_f(sgl), sg_ = sigm_f(sgh);
    sU[lane] = u;

    float s0v = 0.f, va0 = 0.f, va1 = 0.f, va2 = 0.f;
    #pragma unroll 4
    for (int g = 0; g < 64; ++g) {
        s0v += sU[g] * Wr_s2[g*64 + lane];
        float wv = Wr_v[g*64 + lane];
        va0 += sPv0[g]*wv; va1 += sPv1[g]*wv; va2 += sPv2[g]*wv;
    }
    va0 *= sg_; va1 *= sg_; va2 *= sg_;
    sVa0[lane] = va0; sVa1[lane] = va1; sVa2[lane] = va2;

    float vb0 = 0.f, vb1 = 0.f, vb2 = 0.f;
    #pragma unroll 4
    for (int g = 0; g < 64; ++g) {
        float wv = Wr_v2[g*64 + lane];
        vb0 += sVa0[g]*wv; vb1 += sVa1[g]*wv; vb2 += sVa2[g]*wv;
    }
    s0[n*64 + lane] = s0v;
    unsigned short* nd = node_b + (size_t)n * NIN;
    nd[lane] = f2bf(s0v);
    nd[64 + lane*3+0] = f2bf(vb0); nd[64 + lane*3+1] = f2bf(vb1); nd[64 + lane*3+2] = f2bf(vb2);
}

// ---------------- node mix, layer 1 — gather fused ----------------
__global__ __launch_bounds__(256, 6) void node_mix1(const ushort4* __restrict__ Wb, const int* __restrict__ elist,
                                                 const int* __restrict__ offs, const float* __restrict__ sh,
                                                 const int* __restrict__ types,
                                                 const float* __restrict__ Wm, const float* __restrict__ Wp_s,
                                                 const float* __restrict__ Wp_s2, const float* __restrict__ Wsc,
                                                 const float* __restrict__ Wr1, const float* __restrict__ Wr2,
                                                 const float* __restrict__ s0, unsigned short* __restrict__ node_b) {
    int wid = threadIdx.x >> 6, lane = threadIdx.x & 63;
    int n = blockIdx.x * 4 + wid;
    if (n >= NN) return;
    __shared__ __align__(16) float smem[4][1024];
    float* base = &smem[wid][0];

    float s0in = s0[n*64 + lane];

    {
        float arow[16];
        #pragma unroll
        for (int m = 0; m < 16; ++m) arow[m] = 0.0f;
        int e0 = offs[n], e1 = offs[n+1];
        for (int pos = e0; pos < e1; ++pos) {
            int eid = __builtin_amdgcn_readfirstlane(elist[pos]);
            ushort4 wv = Wb[(size_t)pos*64 + lane];
            float wlx = bf2f(wv.x)*0.1f, wly = bf2f(wv.y)*0.1f;
            float wlz = bf2f(wv.z)*0.1f, wlw = bf2f(wv.w)*0.1f;
            const float4* shp = (const float4*)(sh + (size_t)eid*16);
            float4 sa = shp[0], sb = shp[1], sc = shp[2], sd = shp[3];
            arow[0]  += sa.x*wlx;
            arow[1]  += sa.y*wly; arow[2]  += sa.z*wly; arow[3]  += sa.w*wly;
            arow[4]  += sb.x*wlz; arow[5]  += sb.y*wlz; arow[6]  += sb.z*wlz; arow[7] += sb.w*wlz; arow[8] += sc.x*wlz;
            arow[9]  += sc.y*wlw; arow[10] += sc.z*wlw; arow[11] += sc.w*wlw;
            arow[12] += sd.x*wlw; arow[13] += sd.y*wlw; arow[14] += sd.z*wlw; arow[15] += sd.w*wlw;
        }
        #pragma unroll
        for (int m = 0; m < 16; ++m) base[m*64 + lane] = arow[m];
    }

    float acc[16];
    #pragma unroll
    for (int m = 0; m < 16; ++m) acc[m] = 0.0f;
    const float4* A4 = (const float4*)base;
    for (int g4 = 0; g4 < 16; ++g4) {
        int g0 = g4*4;
        float wr1[4], wr2[4], wr3[4], wr0[4];
        #pragma unroll
        for (int gl = 0; gl < 4; ++gl) {
            wr0[gl] = Wm[(g0+gl)*64 + lane];
            wr1[gl] = Wm[4096 + (g0+gl)*64 + lane];
            wr2[gl] = Wm[8192 + (g0+gl)*64 + lane];
            wr3[gl] = Wm[12288 + (g0+gl)*64 + lane];
        }
        #pragma unroll
        for (int m = 0; m < 16; ++m) {
            float4 aq = A4[m*16 + g4];
            const float* wl = (m == 0) ? wr0 : (m < 4) ? wr1 : (m < 9) ? wr2 : wr3;
            acc[m] += aq.x*wl[0] + aq.y*wl[1] + aq.z*wl[2] + aq.w*wl[3];
        }
    }
    float Sv = 0.0f;
    #pragma unroll
    for (int m = 0; m < 16; ++m) Sv += acc[m]*acc[m];

    float* sC  = base + 0;
    float* sSq = base + 64;
    float* sS0 = base + 128;
    float* sP  = base + 192;
    float* sU  = base + 256;

    sC[lane] = acc[0];
    sSq[lane] = Sv;
    sS0[lane] = s0in;

    int t = types[n];
    const float* Bs  = Wp_s  + t*4096;
    const float* Bs2 = Wp_s2 + t*4096;
    const float* Bsc = Wsc   + t*4096;
    float p = 0.f;
    #pragma unroll 4
    for (int g = 0; g < 64; ++g)
        p += Bs[g*64 + lane]*sC[g] + Bs2[g*64 + lane]*sSq[g] + Bsc[g*64 + lane]*sS0[g];
    sP[lane] = p;

    float uq = 0.f;
    #pragma unroll 8
    for (int g = 0; g < 64; ++g) uq += sP[g] * Wr1[g*64 + lane];
    sU[lane] = silu_f(uq);

    float hv = 0.f;
    #pragma unroll 8
    for (int g = 0; g < 64; ++g) hv += sU[g] * Wr2[g*64 + lane];
    node_b[(size_t)n*NIN + 256 + lane] = f2bf(hv);
}

// ---------------- weight transpose + bf16 convert: W[K][N] -> Wt[N][Kpad] ----------------
__global__ __launch_bounds__(256) void wtrans_kernel(const float* __restrict__ W, unsigned short* __restrict__ Wt,
                                                     int Kreal, int Nreal, int Kpad) {
    int idx = blockIdx.x * 256 + threadIdx.x;
    int total = Nreal * Kpad;
    if (idx >= total) return;
    int n = idx / Kpad, k = idx - n*Kpad;
    float v = (k < Kreal) ? W[(size_t)k*Nreal + n] : 0.0f;
    Wt[idx] = f2bf(v);
}

// ---------------- bf16 MFMA GEMM: C = act(A@Bt^T + bias) ----------------
template<int ACT, int BF16OUT>
__global__ __launch_bounds__(256) void gemm_mfma(const unsigned short* __restrict__ Ag, int lda,
                                                 const unsigned short* __restrict__ Bt, int ldb,
                                                 const float* __restrict__ bias, const float* __restrict__ alpha_p,
                                                 void* __restrict__ Cout, int ldc,
                                                 int M, int Nreal, int Nstore, int Kpad) {
    __shared__ __align__(16) unsigned short As[128*40];  // +8 pad
    __shared__ __align__(16) unsigned short Bs[128*40];
    const int tid = threadIdx.x;
    const int bm = blockIdx.y * 128, bn = blockIdx.x * 128;
    const int r = tid >> 1, koff = (tid & 1) * 16;
    const int wave = tid >> 6, lane = tid & 63;
    const int wm = (wave >> 1) * 64, wn = (wave & 1) * 64;
    const int q = lane >> 4, m15 = lane & 15;

    f32x4 acc[4][4];
    #pragma unroll
    for (int i = 0; i < 4; ++i)
        #pragma unroll
        for (int j = 0; j < 4; ++j) acc[i][j] = (f32x4){0.f, 0.f, 0.f, 0.f};

    const bool aok = (bm + r) < M;
    const bool bok = (bn + r) < Nreal;
    const size_t abase = (size_t)(bm + r) * lda + koff;
    const size_t bbase = (size_t)(bn + r) * ldb + koff;

    for (int k0 = 0; k0 < Kpad; k0 += 32) {
        u16x8 av0 = {0,0,0,0,0,0,0,0}, av1 = {0,0,0,0,0,0,0,0};
        u16x8 bv0 = {0,0,0,0,0,0,0,0}, bv1 = {0,0,0,0,0,0,0,0};
        if (aok) { av0 = *(const u16x8*)(Ag + abase + k0); av1 = *(const u16x8*)(Ag + abase + k0 + 8); }
        if (bok) { bv0 = *(const u16x8*)(Bt + bbase + k0); bv1 = *(const u16x8*)(Bt + bbase + k0 + 8); }
        *(u16x8*)&As[r*40 + koff]     = av0;
        *(u16x8*)&As[r*40 + koff + 8] = av1;
        *(u16x8*)&Bs[r*40 + koff]     = bv0;
        *(u16x8*)&Bs[r*40 + koff + 8] = bv1;
        __syncthreads();

        bf16x8 af[4], bfr[4];
        #pragma unroll
        for (int mi = 0; mi < 4; ++mi) af[mi]  = *(const bf16x8*)&As[(wm + mi*16 + m15)*40 + q*8];
        #pragma unroll
        for (int ni = 0; ni < 4; ++ni) bfr[ni] = *(const bf16x8*)&Bs[(wn + ni*16 + m15)*40 + q*8];
        #pragma unroll
        for (int mi = 0; mi < 4; ++mi)
            #pragma unroll
            for (int ni = 0; ni < 4; ++ni)
                acc[mi][ni] = __builtin_amdgcn_mfma_f32_16x16x32_bf16(af[mi], bfr[ni], acc[mi][ni], 0, 0, 0);
        __syncthreads();
    }

    float alpha = (ACT == 1) ? *alpha_p : 0.0f;
    #pragma unroll
    for (int mi = 0; mi < 4; ++mi) {
        int row0 = bm + wm + mi*16 + q*4;
        #pragma unroll
        for (int ni = 0; ni < 4; ++ni) {
            int col = bn + wn + ni*16 + m15;
            #pragma unroll
            for (int rg = 0; rg < 4; ++rg) {
                int row = row0 + rg;
                if (row >= M) continue;
                if (BF16OUT) {
                    if (col >= Nstore) continue;
                    float v = 0.0f;
                    if (col < Nreal) {
                        v = acc[mi][ni][rg] + bias[col];
                        v = (v >= 0.0f) ? v : alpha*v;
                    }
                    ((unsigned short*)Cout)[(size_t)row*ldc + col] = f2bf(v);
                } else {
                    if (col >= Nreal) continue;
                    float v = acc[mi][ni][rg] + bias[col];
                    if (ACT == 1) v = (v >= 0.0f) ? v : alpha*v;
                    else          v = 0.5f * (tanhf(v) + 1.0f);
                    ((float*)Cout)[(size_t)row*ldc + col] = v;
                }
            }
        }
    }
}

// ---------------- scal head ----------------
__global__ __launch_bounds__(256) void scal_kernel(const float* __restrict__ Hs, const float* __restrict__ Ws2,
                                                   const float* __restrict__ bs2, const float* __restrict__ spd,
                                                   float* __restrict__ out) {
    int idx = blockIdx.x * 256 + threadIdx.x;
    int n = idx >> 2, c = idx & 3;
    if (n >= NN) return;
    float acc = bs2[c];
    const float* hr = Hs + (size_t)n * 100;
    #pragma unroll 10
    for (int k = 0; k < 100; ++k) acc += hr[k] * Ws2[k*4 + c];
    acc = fmaxf(acc, 0.0f) * spd[n*4 + c];
    out[(size_t)n*NOUT + 1600 + c] = acc;
}

extern "C" void kernel_launch(void* const* d_in, const int* in_sizes, int n_in,
                              void* d_out, int out_size, void* d_ws, size_t ws_size,
                              hipStream_t stream) {
    const float* x      = (const float*)d_in[0];
    const float* pos    = (const float*)d_in[1];
    const float* shifts = (const float*)d_in[2];
    const float* spd    = (const float*)d_in[3];
    const int*   ei     = (const int*)  d_in[4];
    const float* W_embed= (const float*)d_in[5];
    const float* W_up0  = (const float*)d_in[6];
    const float* r0_w1  = (const float*)d_in[7];
    const float* r0_w2  = (const float*)d_in[9];
    const float* r0_w3  = (const float*)d_in[11];
    const float* Wm0    = (const float*)d_in[12];
    const float* Wp0_s  = (const float*)d_in[13];
    const float* Wp0_s2 = (const float*)d_in[14];
    const float* Wp0_v  = (const float*)d_in[15];
    const float* Wr0_sg = (const float*)d_in[16];
    const float* Wr0_v  = (const float*)d_in[17];
    const float* Wr0_s2 = (const float*)d_in[18];
    const float* Wr0_v2 = (const float*)d_in[19];
    const float* W_up1  = (const float*)d_in[20];
    const float* r1_w1  = (const float*)d_in[21];
    const float* r1_w2  = (const float*)d_in[23];
    const float* r1_w3  = (const float*)d_in[25];
    const float* Wm1    = (const float*)d_in[26];
    const float* Wsc1   = (const float*)d_in[27];
    const float* Wp1_s  = (const float*)d_in[28];
    const float* Wp1_s2 = (const float*)d_in[29];
    const float* Wr1_1  = (const float*)d_in[30];
    const float* Wr1_2  = (const float*)d_in[31];
    const float* Wd1    = (const float*)d_in[32];
    const float* bd1    = (const float*)d_in[33];
    const float* a_d    = (const float*)d_in[34];
    const float* Wd2    = (const float*)d_in[35];
    const float* bd2    = (const float*)d_in[36];
    const float* Ws1    = (const float*)d_in[37];
    const float* bs1    = (const float*)d_in[38];
    const float* a_s    = (const float*)d_in[39];
    const float* Ws2    = (const float*)d_in[40];
    const float* bs2    = (const float*)d_in[41];
    float* out = (float*)d_out;

    char* w = (char*)d_ws;
    int*   types = (int*)  (w + OFF_TYPES);
    float* sh    = (float*)(w + OFF_SH);
    float* ef    = (float*)(w + OFF_EF);
    float* hs    = (float*)(w + OFF_HS);
    ushort4* Wb  = (ushort4*)(w + OFF_A);
    float* s0    = (float*)(w + OFF_S0);
    unsigned short* node_b = (unsigned short*)(w + OFF_NODEB);
    int*   cnt   = (int*)  (w + OFF_CNT);
    int*   offs  = (int*)  (w + OFF_OFFS);
    int*   elist = (int*)  (w + OFF_ELIST);
    unsigned short* H_b   = (unsigned short*)(w + OFF_HB);
    float*          Hs    = (float*)(w + OFF_HSC);
    unsigned short* Wd1t  = (unsigned short*)(w + OFF_WD1T);
    unsigned short* Wd2t  = (unsigned short*)(w + OFF_WD2T);
    unsigned short* Ws1t  = (unsigned short*)(w + OFF_WS1T);

    types_kernel<<<(NN + 255)/256, 256, 0, stream>>>(x, types);
    edge_geom<<<(NE + 255)/256, 256, 0, stream>>>(pos, shifts, ei, sh, ef);

    hipMemsetAsync(cnt, 0, (size_t)NN*4, stream);
    deg_kernel<<<(NE + 255)/256, 256, 0, stream>>>(ef, ei, cnt);
    scan_kernel<<<1, 1024, 0, stream>>>(cnt, offs);
    hipMemsetAsync(cnt, 0, (size_t)NN*4, stream);
    fill_kernel<<<(NE + 255)/256, 256, 0, stream>>>(ef, ei, offs, cnt, elist);

    hs_kernel<<<NN/4, 256, 0, stream>>>(W_embed, types, nullptr, W_up0, hs, 0);
    edge_mlp<<<(NE/GE + 3)/4, 256, 0, stream>>>(ef, ei, elist, offs, hs, r0_w1, r0_w2, r0_w3, Wb);
    node_mix0<<<NN/4, 256, 0, stream>>>(Wb, elist, offs, sh, types, Wm0, Wp0_s, Wp0_s2, Wp0_v,
                                        Wr0_sg, Wr0_s2, Wr0_v, Wr0_v2, s0, node_b);

    hs_kernel<<<NN/4, 256, 0, stream>>>(nullptr, nullptr, s0, W_up1, hs, 1);
    edge_mlp<<<(NE/GE + 3)/4, 256, 0, stream>>>(ef, ei, elist, offs, hs, r1_w1, r1_w2, r1_w3, Wb);
    node_mix1<<<NN/4, 256, 0, stream>>>(Wb, elist, offs, sh, types, Wm1, Wp1_s, Wp1_s2, Wsc1,
                                        Wr1_1, Wr1_2, s0, node_b);

    // weight transposes into the now-dead Wbuf region
    wtrans_kernel<<<(400*320 + 255)/256, 256, 0, stream>>>(Wd1, Wd1t, 320, 400, 320);
    wtrans_kernel<<<(1600*416 + 255)/256, 256, 0, stream>>>(Wd2, Wd2t, 400, 1600, 416);
    wtrans_kernel<<<(100*320 + 255)/256, 256, 0, stream>>>(Ws1, Ws1t, 320, 100, 320);

    // readout: node_b @ Wd1 -> H_b (bf16, K padded to 416); H_b @ Wd2 -> out (tanh-dos)
    gemm_mfma<1,1><<<dim3(4, 157), 256, 0, stream>>>(node_b, NIN, Wd1t, 320, bd1, a_d, H_b, 416, NN, 400, 416, 320);
    gemm_mfma<2,0><<<dim3(13, 157), 256, 0, stream>>>(H_b, 416, Wd2t, 416, bd2, a_d, out, NOUT, NN, 1600, 1600, 416);
    gemm_mfma<1,0><<<dim3(1, 157), 256, 0, stream>>>(node_b, NIN, Ws1t, 320, bs1, a_s, Hs, 100, NN, 100, 100, 320);
    scal_kernel<<<(NN*4 + 255)/256, 256, 0, stream>>>(Hs, Ws2, bs2, spd, out);
}

// Round 11
// 906.132 us; speedup vs baseline: 1.8014x; 1.0082x over previous
//
#include <hip/hip_runtime.h>
#include <math.h>

#define NN 20000
#define NE 200000
#define NZ 10
#define NF 64
#define NWIN 400
#define NIN 320
#define NOUT 1604
#define GE 16   // edges per wave in edge_mlp

// ---------- workspace layout (bytes) ----------
#define OFF_TYPES   ((size_t)0)
#define OFF_SH      ((size_t)81920)
#define OFF_EF      (OFF_SH + (size_t)NE*16*4)
#define OFF_HS      (OFF_EF + (size_t)NE*8*4)
#define OFF_A       (OFF_HS + (size_t)NN*64*4)          // 24,401,920
#define A_BYTES     ((size_t)NN*1024*4)                 // 81,920,000 (Wbuf: bf16x4 per lane, cap 160K edges)
#define OFF_S0      (OFF_A + A_BYTES)
#define OFF_NODEB   (OFF_S0 + (size_t)NN*64*4)          // bf16 node [NN][320]
#define OFF_CNT     (OFF_NODEB + (size_t)NN*NIN*2)
#define OFF_OFFS    (OFF_CNT + (size_t)NN*4)
#define OFF_ELIST   (OFF_OFFS + (size_t)(NN+1)*4 + 12)
// post-node_mix1 aliases inside the (dead) Wbuf/A region:
#define OFF_HB      OFF_A                               // bf16 H [NN][416]
#define OFF_HSC     (OFF_A + (size_t)20000000)          // fp32 Hs [NN][100]
#define OFF_WD1T    (OFF_A + (size_t)30000000)          // bf16 [400][320]
#define OFF_WD2T    (OFF_A + (size_t)31000000)          // bf16 [1600][416]
#define OFF_WS1T    (OFF_A + (size_t)33000000)          // bf16 [100][320]

typedef __attribute__((ext_vector_type(8))) short bf16x8;
typedef __attribute__((ext_vector_type(8))) unsigned short u16x8;
typedef __attribute__((ext_vector_type(4))) float f32x4;

__device__ __forceinline__ void wave_sync() {
    __asm__ volatile("" ::: "memory");
    __builtin_amdgcn_wave_barrier();
    __asm__ volatile("" ::: "memory");
}
__device__ __forceinline__ float silu_f(float x)  { return x / (1.0f + __expf(-x)); }
__device__ __forceinline__ float sigm_f(float x)  { return 1.0f / (1.0f + __expf(-x)); }
__device__ __forceinline__ unsigned short f2bf(float v) {
    unsigned int u = __float_as_uint(v);
    unsigned int r = (u + 0x7fffu + ((u >> 16) & 1u)) >> 16;
    return (unsigned short)r;
}
__device__ __forceinline__ float bf2f(unsigned short v) {
    return __uint_as_float(((unsigned int)v) << 16);
}

// ---------------- types (one-hot -> int) ----------------
__global__ __launch_bounds__(256) void types_kernel(const float* __restrict__ x, int* __restrict__ types) {
    int n = blockIdx.x * 256 + threadIdx.x;
    if (n >= NN) return;
    int t = 0;
    #pragma unroll
    for (int z = 0; z < NZ; ++z) if (x[n*NZ + z] != 0.0f) t = z;
    types[n] = t;
}

// ---------------- edge geometry: sph(16) + radial basis(8) ----------------
__global__ __launch_bounds__(256) void edge_geom(const float* __restrict__ pos, const float* __restrict__ shifts,
                                                 const int* __restrict__ ei, float* __restrict__ sh, float* __restrict__ ef) {
    int e = blockIdx.x * 256 + threadIdx.x;
    if (e >= NE) return;
    int s = ei[e], rv = ei[NE + e];
    float vx = pos[rv*3+0] - pos[s*3+0] + shifts[e*3+0];
    float vy = pos[rv*3+1] - pos[s*3+1] + shifts[e*3+1];
    float vz = pos[rv*3+2] - pos[s*3+2] + shifts[e*3+2];
    float r = sqrtf(vx*vx + vy*vy + vz*vz) + 1e-9f;
    float inv = 1.0f / r;
    float x = vx*inv, y = vy*inv, z = vz*inv;

    const float s3  = 1.7320508075688772f;
    const float s15 = 3.872983346207417f;
    const float s5  = 2.23606797749979f;
    const float s358 = 2.0916500663351889f;
    const float s105 = 10.246950765959598f;
    const float s218 = 1.6201851746019651f;
    const float s7  = 2.6457513110645907f;
    float o[16];
    o[0] = 1.0f;
    o[1] = s3*x; o[2] = s3*y; o[3] = s3*z;
    o[4] = s15*x*y; o[5] = s15*y*z; o[6] = 0.5f*s5*(3.0f*z*z - 1.0f);
    o[7] = s15*x*z; o[8] = 0.5f*s15*(x*x - y*y);
    o[9]  = s358*y*(3.0f*x*x - y*y);
    o[10] = s105*x*y*z;
    o[11] = s218*y*(5.0f*z*z - 1.0f);
    o[12] = 0.5f*s7*(5.0f*z*z*z - 3.0f*z);
    o[13] = s218*x*(5.0f*z*z - 1.0f);
    o[14] = 0.5f*s105*(x*x - y*y)*z;
    o[15] = s358*x*(x*x - 3.0f*y*y);
    #pragma unroll
    for (int i = 0; i < 16; ++i) sh[e*16 + i] = o[i];

    float t = r * 0.2f;
    float env = 0.0f;
    if (t < 1.0f) {
        float t2 = t*t, t4 = t2*t2, t5 = t4*t;
        env = 1.0f - 21.0f*t5 + 35.0f*t5*t - 15.0f*t5*t2;
    }
    float c0 = 0.6324555320336759f;
    float a = 0.6283185307179586f * r;
    #pragma unroll
    for (int k = 0; k < 8; ++k)
        ef[e*8 + k] = c0 * sinf((float)(k+1) * a) * inv * env;
}

// ---------------- edge bucketing by receiver ----------------
__global__ __launch_bounds__(256) void deg_kernel(const float* __restrict__ ef, const int* __restrict__ ei,
                                                  int* __restrict__ cnt) {
    int e = blockIdx.x * 256 + threadIdx.x;
    if (e >= NE) return;
    if (ef[e*8] != 0.0f) atomicAdd(&cnt[ei[NE + e]], 1);
}

__global__ __launch_bounds__(1024) void scan_kernel(const int* __restrict__ cnt, int* __restrict__ offs) {
    __shared__ int part[1024];
    int t = threadIdx.x;
    int loc[20]; int s = 0;
    #pragma unroll
    for (int i = 0; i < 20; ++i) { int idx = t*20 + i; int c = (idx < NN) ? cnt[idx] : 0; loc[i] = s; s += c; }
    part[t] = s; __syncthreads();
    for (int d = 1; d < 1024; d <<= 1) {
        int v = 0; if (t >= d) v = part[t-d];
        __syncthreads();
        if (t >= d) part[t] += v;
        __syncthreads();
    }
    int pre = (t == 0) ? 0 : part[t-1];
    #pragma unroll
    for (int i = 0; i < 20; ++i) { int idx = t*20 + i; if (idx < NN) offs[idx] = pre + loc[i]; }
    if (t == 1023) offs[NN] = part[1023];
}

__global__ __launch_bounds__(256) void fill_kernel(const float* __restrict__ ef, const int* __restrict__ ei,
                                                   const int* __restrict__ offs, int* __restrict__ cur,
                                                   int* __restrict__ elist) {
    int e = blockIdx.x * 256 + threadIdx.x;
    if (e >= NE) return;
    if (ef[e*8] != 0.0f) {
        int r = ei[NE + e];
        int slot = offs[r] + atomicAdd(&cur[r], 1);
        elist[slot] = e;
    }
}

// ---------------- hs = hs_in @ W_up  (wave per node) ----------------
__global__ __launch_bounds__(256) void hs_kernel(const float* __restrict__ Wemb, const int* __restrict__ types,
                                                 const float* __restrict__ s0, const float* __restrict__ Wup,
                                                 float* __restrict__ hs, int mode) {
    int wid = threadIdx.x >> 6, lane = threadIdx.x & 63;
    int n = blockIdx.x * 4 + wid;
    if (n >= NN) return;
    __shared__ float sIn[4][64];
    if (mode == 0) { int t = types[n]; sIn[wid][lane] = Wemb[t*64 + lane]; }
    else           { sIn[wid][lane] = s0[n*64 + lane]; }
    wave_sync();
    float acc = 0.0f;
    #pragma unroll 8
    for (int g = 0; g < 64; ++g) acc += sIn[wid][g] * Wup[g*64 + lane];
    hs[n*64 + lane] = acc;
}

// ---------------- edge MLP: wl[pos][lane] = (hid@w3)[lane] * hs[snd][lane] ----------------
__global__ __launch_bounds__(256) void edge_mlp(const float* __restrict__ ef, const int* __restrict__ ei,
                                                const int* __restrict__ elist, const int* __restrict__ offs,
                                                const float* __restrict__ hs, const float* __restrict__ w1,
                                                const float* __restrict__ w2, const float* __restrict__ w3,
                                                ushort4* __restrict__ Wb) {
    int wid = threadIdx.x >> 6, lane = threadIdx.x & 63;
    int Ea = offs[NN];
    int base = (blockIdx.x * 4 + wid) * GE;
    if (base >= Ea) return;
    int ne = min(GE, Ea - base);

    __shared__ int sE[4][GE], sSND[4][GE];
    __shared__ __align__(16) float sEF[4][GE][8];
    __shared__ __align__(16) float sHH[4][GE][64];   // h1, then overwritten with h2

    if (lane < ne) {
        int e = elist[base + lane];
        sE[wid][lane] = e; sSND[wid][lane] = ei[e];
    }
    wave_sync();
    #pragma unroll
    for (int p = 0; p < 2; ++p) {   // stage ef: GE*8 = 128 slots (zero-padded)
        int i = p*64 + lane; int el = i >> 3, k = i & 7;
        float v = 0.0f; if (el < ne) v = ef[(size_t)sE[wid][el]*8 + k];
        sEF[wid][el][k] = v;
    }
    wave_sync();

    float w1c[8];
    #pragma unroll
    for (int k = 0; k < 8; ++k) w1c[k] = w1[k*64 + lane];

    // h1[e][lane]
    #pragma unroll
    for (int e = 0; e < GE; ++e) {
        const float4* efp = (const float4*)&sEF[wid][e][0];
        float4 a = efp[0], b = efp[1];
        float s = a.x*w1c[0] + a.y*w1c[1] + a.z*w1c[2] + a.w*w1c[3]
                + b.x*w1c[4] + b.y*w1c[5] + b.z*w1c[6] + b.w*w1c[7];
        sHH[wid][e][lane] = silu_f(s);
    }
    wave_sync();

    // h2[e] in registers: w2 loads amortized over GE edges
    float hv[GE];
    #pragma unroll
    for (int e = 0; e < GE; ++e) hv[e] = 0.0f;
    for (int j4 = 0; j4 < 16; ++j4) {
        float w20 = w2[(j4*4+0)*64 + lane];
        float w21 = w2[(j4*4+1)*64 + lane];
        float w22 = w2[(j4*4+2)*64 + lane];
        float w23 = w2[(j4*4+3)*64 + lane];
        #pragma unroll
        for (int e = 0; e < GE; ++e) {
            float4 hq = *(const float4*)&sHH[wid][e][j4*4];   // broadcast
            hv[e] += hq.x*w20 + hq.y*w21 + hq.z*w22 + hq.w*w23;
        }
    }
    wave_sync();
    #pragma unroll
    for (int e = 0; e < GE; ++e) sHH[wid][e][lane] = silu_f(hv[e]);   // reuse buffer
    wave_sync();

    // W[e]: w3 loads amortized over GE edges
    float4 W[GE];
    #pragma unroll
    for (int e = 0; e < GE; ++e) { W[e].x = 0.f; W[e].y = 0.f; W[e].z = 0.f; W[e].w = 0.f; }
    const float4* w3v = (const float4*)w3;
    for (int j4 = 0; j4 < 16; ++j4) {
        float4 r0 = w3v[(j4*4+0)*64 + lane];
        float4 r1 = w3v[(j4*4+1)*64 + lane];
        float4 r2 = w3v[(j4*4+2)*64 + lane];
        float4 r3 = w3v[(j4*4+3)*64 + lane];
        #pragma unroll
        for (int e = 0; e < GE; ++e) {
            float4 hq = *(const float4*)&sHH[wid][e][j4*4];   // broadcast
            W[e].x += hq.x*r0.x + hq.y*r1.x + hq.z*r2.x + hq.w*r3.x;
            W[e].y += hq.x*r0.y + hq.y*r1.y + hq.z*r2.y + hq.w*r3.y;
            W[e].z += hq.x*r0.z + hq.y*r1.z + hq.z*r2.z + hq.w*r3.z;
            W[e].w += hq.x*r0.w + hq.y*r1.w + hq.z*r2.w + hq.w*r3.w;
        }
    }

    // fold hs[snd] and store bf16x4 (static W index + wave-uniform guard)
    #pragma unroll
    for (int i = 0; i < GE; ++i) {
        if (i < ne) {
            float hsv = hs[(size_t)sSND[wid][i]*64 + lane];
            ushort4 o;
            o.x = f2bf(W[i].x * hsv);
            o.y = f2bf(W[i].y * hsv);
            o.z = f2bf(W[i].z * hsv);
            o.w = f2bf(W[i].w * hsv);
            Wb[(size_t)(base + i)*64 + lane] = o;
        }
    }
}

// ---------------- node mix, layer 0 — gather fused, float4 LDS reads, 8 waves/EU ----------------
__global__ __launch_bounds__(256, 8) void node_mix0(const ushort4* __restrict__ Wb, const int* __restrict__ elist,
                                                 const int* __restrict__ offs, const float* __restrict__ sh,
                                                 const int* __restrict__ types,
                                                 const float* __restrict__ Wm, const float* __restrict__ Wp_s,
                                                 const float* __restrict__ Wp_s2, const float* __restrict__ Wp_v,
                                                 const float* __restrict__ Wr_sg, const float* __restrict__ Wr_s2,
                                                 const float* __restrict__ Wr_v, const float* __restrict__ Wr_v2,
                                                 float* __restrict__ s0, unsigned short* __restrict__ node_b) {
    int wid = threadIdx.x >> 6, lane = threadIdx.x & 63;
    int n = blockIdx.x * 4 + wid;
    if (n >= NN) return;
    __shared__ __align__(16) float smem[4][1024];
    float* base = &smem[wid][0];

    // gather prologue: A row built in registers from Wbuf + sh
    {
        float arow[16];
        #pragma unroll
        for (int m = 0; m < 16; ++m) arow[m] = 0.0f;
        int e0 = offs[n], e1 = offs[n+1];
        for (int pos = e0; pos < e1; ++pos) {
            int eid = __builtin_amdgcn_readfirstlane(elist[pos]);
            ushort4 wv = Wb[(size_t)pos*64 + lane];
            float wlx = bf2f(wv.x)*0.1f, wly = bf2f(wv.y)*0.1f;
            float wlz = bf2f(wv.z)*0.1f, wlw = bf2f(wv.w)*0.1f;
            const float4* shp = (const float4*)(sh + (size_t)eid*16);
            float4 sa = shp[0], sb = shp[1], sc = shp[2], sd = shp[3];   // uniform
            arow[0]  += sa.x*wlx;
            arow[1]  += sa.y*wly; arow[2]  += sa.z*wly; arow[3]  += sa.w*wly;
            arow[4]  += sb.x*wlz; arow[5]  += sb.y*wlz; arow[6]  += sb.z*wlz; arow[7] += sb.w*wlz; arow[8] += sc.x*wlz;
            arow[9]  += sc.y*wlw; arow[10] += sc.z*wlw; arow[11] += sc.w*wlw;
            arow[12] += sd.x*wlw; arow[13] += sd.y*wlw; arow[14] += sd.z*wlw; arow[15] += sd.w*wlw;
        }
        #pragma unroll
        for (int m = 0; m < 16; ++m) base[m*64 + lane] = arow[m];
    }

    float acc[16];
    #pragma unroll
    for (int m = 0; m < 16; ++m) acc[m] = 0.0f;
    const float4* A4 = (const float4*)base;
    for (int g4 = 0; g4 < 16; ++g4) {
        int g0 = g4*4;
        float wr1[4], wr2[4], wr3[4], wr0[4];
        #pragma unroll
        for (int gl = 0; gl < 4; ++gl) {
            wr0[gl] = Wm[(g0+gl)*64 + lane];
            wr1[gl] = Wm[4096 + (g0+gl)*64 + lane];
            wr2[gl] = Wm[8192 + (g0+gl)*64 + lane];
            wr3[gl] = Wm[12288 + (g0+gl)*64 + lane];
        }
        #pragma unroll
        for (int m = 0; m < 16; ++m) {
            float4 aq = A4[m*16 + g4];
            const float* wl = (m == 0) ? wr0 : (m < 4) ? wr1 : (m < 9) ? wr2 : wr3;
            acc[m] += aq.x*wl[0] + aq.y*wl[1] + aq.z*wl[2] + aq.w*wl[3];
        }
    }
    float Sv = 0.0f;
    #pragma unroll
    for (int m = 0; m < 16; ++m) Sv += acc[m]*acc[m];

    // wave-private alias of the (now-consumed) A slice
    float* sPk0 = base + 0;
    float* sPk1 = base + 64;
    float* sPk2 = base + 128;
    float* sPk3 = base + 192;
    float* sSq  = base + 256;
    float* sPs  = base + 320;
    float* sPv0 = base + 384;
    float* sPv1 = base + 448;
    float* sPv2 = base + 512;
    float* sU   = base + 576;
    float* sVa0 = base + 640;
    float* sVa1 = base + 704;
    float* sVa2 = base + 768;

    sPk0[lane] = acc[0]; sPk1[lane] = acc[1];
    sPk2[lane] = acc[2]; sPk3[lane] = acc[3];
    sSq[lane] = Sv;

    int t = types[n];
    const float* Bs  = Wp_s  + t*4096;
    const float* Bs2 = Wp_s2 + t*4096;
    const float* Bv  = Wp_v  + t*4096;
    float ps = 0.f, pv0 = 0.f, pv1 = 0.f, pv2 = 0.f;
    #pragma unroll 1
    for (int g4 = 0; g4 < 16; ++g4) {
        int g0 = g4*4;
        float4 k0 = *(const float4*)&sPk0[g0];
        float4 k1 = *(const float4*)&sPk1[g0];
        float4 k2 = *(const float4*)&sPk2[g0];
        float4 k3 = *(const float4*)&sPk3[g0];
        float4 sq = *(const float4*)&sSq[g0];
        ps += Bs[(g0+0)*64 + lane]*k0.x + Bs2[(g0+0)*64 + lane]*sq.x
            + Bs[(g0+1)*64 + lane]*k0.y + Bs2[(g0+1)*64 + lane]*sq.y
            + Bs[(g0+2)*64 + lane]*k0.z + Bs2[(g0+2)*64 + lane]*sq.z
            + Bs[(g0+3)*64 + lane]*k0.w + Bs2[(g0+3)*64 + lane]*sq.w;
        float bv0 = Bv[(g0+0)*64 + lane], bv1 = Bv[(g0+1)*64 + lane];
        float bv2 = Bv[(g0+2)*64 + lane], bv3 = Bv[(g0+3)*64 + lane];
        pv0 += bv0*k1.x + bv1*k1.y + bv2*k1.z + bv3*k1.w;
        pv1 += bv0*k2.x + bv1*k2.y + bv2*k2.z + bv3*k2.w;
        pv2 += bv0*k3.x + bv1*k3.y + bv2*k3.z + bv3*k3.w;
    }
    sPs[lane] = ps;
    sPv0[lane] = pv0; sPv1[lane] = pv1; sPv2[lane] = pv2;

    float sgl = 0.f, sgh = 0.f;
    #pragma unroll 1
    for (int g4 = 0; g4 < 16; ++g4) {
        int g0 = g4*4;
        float4 p = *(const float4*)&sPs[g0];
        sgl += p.x*Wr_sg[(g0+0)*128 + lane] + p.y*Wr_sg[(g0+1)*128 + lane]
             + p.z*Wr_sg[(g0+2)*128 + lane] + p.w*Wr_sg[(g0+3)*128 + lane];
        sgh += p.x*Wr_sg[(g0+0)*128 + 64 + lane] + p.y*Wr_sg[(g0+1)*128 + 64 + lane]
             + p.z*Wr_sg[(g0+2)*128 + 64 + lane] + p.w*Wr_sg[(g0+3)*128 + 64 + lane];
    }
    float u = silu_f(sgl), sg_ = sigm_f(sgh);
    sU[lane] = u;

    float s0v = 0.f, va0 = 0.f, va1 = 0.f, va2 = 0.f;
    #pragma unroll 1
    for (int g4 = 0; g4 < 16; ++g4) {
        int g0 = g4*4;
        float4 uq = *(const float4*)&sU[g0];
        float4 p0 = *(const float4*)&sPv0[g0];
        float4 p1 = *(const float4*)&sPv1[g0];
        float4 p2 = *(const float4*)&sPv2[g0];
        s0v += uq.x*Wr_s2[(g0+0)*64 + lane] + uq.y*Wr_s2[(g0+1)*64 + lane]
             + uq.z*Wr_s2[(g0+2)*64 + lane] + uq.w*Wr_s2[(g0+3)*64 + lane];
        float wv0 = Wr_v[(g0+0)*64 + lane], wv1 = Wr_v[(g0+1)*64 + lane];
        float wv2 = Wr_v[(g0+2)*64 + lane], wv3 = Wr_v[(g0+3)*64 + lane];
        va0 += p0.x*wv0 + p0.y*wv1 + p0.z*wv2 + p0.w*wv3;
        va1 += p1.x*wv0 + p1.y*wv1 + p1.z*wv2 + p1.w*wv3;
        va2 += p2.x*wv0 + p2.y*wv1 + p2.z*wv2 + p2.w*wv3;
    }
    va0 *= sg_; va1 *= sg_; va2 *= sg_;
    sVa0[lane] = va0; sVa1[lane] = va1; sVa2[lane] = va2;

    float vb0 = 0.f, vb1 = 0.f, vb2 = 0.f;
    #pragma unroll 1
    for (int g4 = 0; g4 < 16; ++g4) {
        int g0 = g4*4;
        float4 a0 = *(const float4*)&sVa0[g0];
        float4 a1 = *(const float4*)&sVa1[g0];
        float4 a2 = *(const float4*)&sVa2[g0];
        float wv0 = Wr_v2[(g0+0)*64 + lane], wv1 = Wr_v2[(g0+1)*64 + lane];
        float wv2 = Wr_v2[(g0+2)*64 + lane], wv3 = Wr_v2[(g0+3)*64 + lane];
        vb0 += a0.x*wv0 + a0.y*wv1 + a0.z*wv2 + a0.w*wv3;
        vb1 += a1.x*wv0 + a1.y*wv1 + a1.z*wv2 + a1.w*wv3;
        vb2 += a2.x*wv0 + a2.y*wv1 + a2.z*wv2 + a2.w*wv3;
    }
    s0[n*64 + lane] = s0v;
    unsigned short* nd = node_b + (size_t)n * NIN;
    nd[lane] = f2bf(s0v);
    nd[64 + lane*3+0] = f2bf(vb0); nd[64 + lane*3+1] = f2bf(vb1); nd[64 + lane*3+2] = f2bf(vb2);
}

// ---------------- node mix, layer 1 — gather fused, float4 LDS reads, 8 waves/EU ----------------
__global__ __launch_bounds__(256, 8) void node_mix1(const ushort4* __restrict__ Wb, const int* __restrict__ elist,
                                                 const int* __restrict__ offs, const float* __restrict__ sh,
                                                 const int* __restrict__ types,
                                                 const float* __restrict__ Wm, const float* __restrict__ Wp_s,
                                                 const float* __restrict__ Wp_s2, const float* __restrict__ Wsc,
                                                 const float* __restrict__ Wr1, const float* __restrict__ Wr2,
                                                 const float* __restrict__ s0, unsigned short* __restrict__ node_b) {
    int wid = threadIdx.x >> 6, lane = threadIdx.x & 63;
    int n = blockIdx.x * 4 + wid;
    if (n >= NN) return;
    __shared__ __align__(16) float smem[4][1024];
    float* base = &smem[wid][0];

    float s0in = s0[n*64 + lane];

    {
        float arow[16];
        #pragma unroll
        for (int m = 0; m < 16; ++m) arow[m] = 0.0f;
        int e0 = offs[n], e1 = offs[n+1];
        for (int pos = e0; pos < e1; ++pos) {
            int eid = __builtin_amdgcn_readfirstlane(elist[pos]);
            ushort4 wv = Wb[(size_t)pos*64 + lane];
            float wlx = bf2f(wv.x)*0.1f, wly = bf2f(wv.y)*0.1f;
            float wlz = bf2f(wv.z)*0.1f, wlw = bf2f(wv.w)*0.1f;
            const float4* shp = (const float4*)(sh + (size_t)eid*16);
            float4 sa = shp[0], sb = shp[1], sc = shp[2], sd = shp[3];
            arow[0]  += sa.x*wlx;
            arow[1]  += sa.y*wly; arow[2]  += sa.z*wly; arow[3]  += sa.w*wly;
            arow[4]  += sb.x*wlz; arow[5]  += sb.y*wlz; arow[6]  += sb.z*wlz; arow[7] += sb.w*wlz; arow[8] += sc.x*wlz;
            arow[9]  += sc.y*wlw; arow[10] += sc.z*wlw; arow[11] += sc.w*wlw;
            arow[12] += sd.x*wlw; arow[13] += sd.y*wlw; arow[14] += sd.z*wlw; arow[15] += sd.w*wlw;
        }
        #pragma unroll
        for (int m = 0; m < 16; ++m) base[m*64 + lane] = arow[m];
    }

    float acc[16];
    #pragma unroll
    for (int m = 0; m < 16; ++m) acc[m] = 0.0f;
    const float4* A4 = (const float4*)base;
    for (int g4 = 0; g4 < 16; ++g4) {
        int g0 = g4*4;
        float wr1[4], wr2[4], wr3[4], wr0[4];
        #pragma unroll
        for (int gl = 0; gl < 4; ++gl) {
            wr0[gl] = Wm[(g0+gl)*64 + lane];
            wr1[gl] = Wm[4096 + (g0+gl)*64 + lane];
            wr2[gl] = Wm[8192 + (g0+gl)*64 + lane];
            wr3[gl] = Wm[12288 + (g0+gl)*64 + lane];
        }
        #pragma unroll
        for (int m = 0; m < 16; ++m) {
            float4 aq = A4[m*16 + g4];
            const float* wl = (m == 0) ? wr0 : (m < 4) ? wr1 : (m < 9) ? wr2 : wr3;
            acc[m] += aq.x*wl[0] + aq.y*wl[1] + aq.z*wl[2] + aq.w*wl[3];
        }
    }
    float Sv = 0.0f;
    #pragma unroll
    for (int m = 0; m < 16; ++m) Sv += acc[m]*acc[m];

    float* sC  = base + 0;
    float* sSq = base + 64;
    float* sS0 = base + 128;
    float* sP  = base + 192;
    float* sU  = base + 256;

    sC[lane] = acc[0];
    sSq[lane] = Sv;
    sS0[lane] = s0in;

    int t = types[n];
    const float* Bs  = Wp_s  + t*4096;
    const float* Bs2 = Wp_s2 + t*4096;
    const float* Bsc = Wsc   + t*4096;
    float p = 0.f;
    #pragma unroll 1
    for (int g4 = 0; g4 < 16; ++g4) {
        int g0 = g4*4;
        float4 cq  = *(const float4*)&sC [g0];
        float4 sq  = *(const float4*)&sSq[g0];
        float4 s0q = *(const float4*)&sS0[g0];
        p += Bs[(g0+0)*64 + lane]*cq.x + Bs2[(g0+0)*64 + lane]*sq.x + Bsc[(g0+0)*64 + lane]*s0q.x
           + Bs[(g0+1)*64 + lane]*cq.y + Bs2[(g0+1)*64 + lane]*sq.y + Bsc[(g0+1)*64 + lane]*s0q.y
           + Bs[(g0+2)*64 + lane]*cq.z + Bs2[(g0+2)*64 + lane]*sq.z + Bsc[(g0+2)*64 + lane]*s0q.z
           + Bs[(g0+3)*64 + lane]*cq.w + Bs2[(g0+3)*64 + lane]*sq.w + Bsc[(g0+3)*64 + lane]*s0q.w;
    }
    sP[lane] = p;

    float uq = 0.f;
    #pragma unroll 1
    for (int g4 = 0; g4 < 16; ++g4) {
        int g0 = g4*4;
        float4 pq = *(const float4*)&sP[g0];
        uq += pq.x*Wr1[(g0+0)*64 + lane] + pq.y*Wr1[(g0+1)*64 + lane]
            + pq.z*Wr1[(g0+2)*64 + lane] + pq.w*Wr1[(g0+3)*64 + lane];
    }
    sU[lane] = silu_f(uq);

    float hv = 0.f;
    #pragma unroll 1
    for (int g4 = 0; g4 < 16; ++g4) {
        int g0 = g4*4;
        float4 uq4 = *(const float4*)&sU[g0];
        hv += uq4.x*Wr2[(g0+0)*64 + lane] + uq4.y*Wr2[(g0+1)*64 + lane]
            + uq4.z*Wr2[(g0+2)*64 + lane] + uq4.w*Wr2[(g0+3)*64 + lane];
    }
    node_b[(size_t)n*NIN + 256 + lane] = f2bf(hv);
}

// ---------------- weight transpose + bf16 convert: W[K][N] -> Wt[N][Kpad] ----------------
__global__ __launch_bounds__(256) void wtrans_kernel(const float* __restrict__ W, unsigned short* __restrict__ Wt,
                                                     int Kreal, int Nreal, int Kpad) {
    int idx = blockIdx.x * 256 + threadIdx.x;
    int total = Nreal * Kpad;
    if (idx >= total) return;
    int n = idx / Kpad, k = idx - n*Kpad;
    float v = (k < Kreal) ? W[(size_t)k*Nreal + n] : 0.0f;
    Wt[idx] = f2bf(v);
}

// ---------------- bf16 MFMA GEMM: C = act(A@Bt^T + bias) ----------------
template<int ACT, int BF16OUT>
__global__ __launch_bounds__(256) void gemm_mfma(const unsigned short* __restrict__ Ag, int lda,
                                                 const unsigned short* __restrict__ Bt, int ldb,
                                                 const float* __restrict__ bias, const float* __restrict__ alpha_p,
                                                 void* __restrict__ Cout, int ldc,
                                                 int M, int Nreal, int Nstore, int Kpad) {
    __shared__ __align__(16) unsigned short As[128*40];  // +8 pad
    __shared__ __align__(16) unsigned short Bs[128*40];
    const int tid = threadIdx.x;
    const int bm = blockIdx.y * 128, bn = blockIdx.x * 128;
    const int r = tid >> 1, koff = (tid & 1) * 16;
    const int wave = tid >> 6, lane = tid & 63;
    const int wm = (wave >> 1) * 64, wn = (wave & 1) * 64;
    const int q = lane >> 4, m15 = lane & 15;

    f32x4 acc[4][4];
    #pragma unroll
    for (int i = 0; i < 4; ++i)
        #pragma unroll
        for (int j = 0; j < 4; ++j) acc[i][j] = (f32x4){0.f, 0.f, 0.f, 0.f};

    const bool aok = (bm + r) < M;
    const bool bok = (bn + r) < Nreal;
    const size_t abase = (size_t)(bm + r) * lda + koff;
    const size_t bbase = (size_t)(bn + r) * ldb + koff;

    for (int k0 = 0; k0 < Kpad; k0 += 32) {
        u16x8 av0 = {0,0,0,0,0,0,0,0}, av1 = {0,0,0,0,0,0,0,0};
        u16x8 bv0 = {0,0,0,0,0,0,0,0}, bv1 = {0,0,0,0,0,0,0,0};
        if (aok) { av0 = *(const u16x8*)(Ag + abase + k0); av1 = *(const u16x8*)(Ag + abase + k0 + 8); }
        if (bok) { bv0 = *(const u16x8*)(Bt + bbase + k0); bv1 = *(const u16x8*)(Bt + bbase + k0 + 8); }
        *(u16x8*)&As[r*40 + koff]     = av0;
        *(u16x8*)&As[r*40 + koff + 8] = av1;
        *(u16x8*)&Bs[r*40 + koff]     = bv0;
        *(u16x8*)&Bs[r*40 + koff + 8] = bv1;
        __syncthreads();

        bf16x8 af[4], bfr[4];
        #pragma unroll
        for (int mi = 0; mi < 4; ++mi) af[mi]  = *(const bf16x8*)&As[(wm + mi*16 + m15)*40 + q*8];
        #pragma unroll
        for (int ni = 0; ni < 4; ++ni) bfr[ni] = *(const bf16x8*)&Bs[(wn + ni*16 + m15)*40 + q*8];
        #pragma unroll
        for (int mi = 0; mi < 4; ++mi)
            #pragma unroll
            for (int ni = 0; ni < 4; ++ni)
                acc[mi][ni] = __builtin_amdgcn_mfma_f32_16x16x32_bf16(af[mi], bfr[ni], acc[mi][ni], 0, 0, 0);
        __syncthreads();
    }

    float alpha = (ACT == 1) ? *alpha_p : 0.0f;
    #pragma unroll
    for (int mi = 0; mi < 4; ++mi) {
        int row0 = bm + wm + mi*16 + q*4;
        #pragma unroll
        for (int ni = 0; ni < 4; ++ni) {
            int col = bn + wn + ni*16 + m15;
            #pragma unroll
            for (int rg = 0; rg < 4; ++rg) {
                int row = row0 + rg;
                if (row >= M) continue;
                if (BF16OUT) {
                    if (col >= Nstore) continue;
                    float v = 0.0f;
                    if (col < Nreal) {
                        v = acc[mi][ni][rg] + bias[col];
                        v = (v >= 0.0f) ? v : alpha*v;
                    }
                    ((unsigned short*)Cout)[(size_t)row*ldc + col] = f2bf(v);
                } else {
                    if (col >= Nreal) continue;
                    float v = acc[mi][ni][rg] + bias[col];
                    if (ACT == 1) v = (v >= 0.0f) ? v : alpha*v;
                    else          v = 0.5f * (tanhf(v) + 1.0f);
                    ((float*)Cout)[(size_t)row*ldc + col] = v;
                }
            }
        }
    }
}

// ---------------- scal head ----------------
__global__ __launch_bounds__(256) void scal_kernel(const float* __restrict__ Hs, const float* __restrict__ Ws2,
                                                   const float* __restrict__ bs2, const float* __restrict__ spd,
                                                   float* __restrict__ out) {
    int idx = blockIdx.x * 256 + threadIdx.x;
    int n = idx >> 2, c = idx & 3;
    if (n >= NN) return;
    float acc = bs2[c];
    const float* hr = Hs + (size_t)n * 100;
    #pragma unroll 10
    for (int k = 0; k < 100; ++k) acc += hr[k] * Ws2[k*4 + c];
    acc = fmaxf(acc, 0.0f) * spd[n*4 + c];
    out[(size_t)n*NOUT + 1600 + c] = acc;
}

extern "C" void kernel_launch(void* const* d_in, const int* in_sizes, int n_in,
                              void* d_out, int out_size, void* d_ws, size_t ws_size,
                              hipStream_t stream) {
    const float* x      = (const float*)d_in[0];
    const float* pos    = (const float*)d_in[1];
    const float* shifts = (const float*)d_in[2];
    const float* spd    = (const float*)d_in[3];
    const int*   ei     = (const int*)  d_in[4];
    const float* W_embed= (const float*)d_in[5];
    const float* W_up0  = (const float*)d_in[6];
    const float* r0_w1  = (const float*)d_in[7];
    const float* r0_w2  = (const float*)d_in[9];
    const float* r0_w3  = (const float*)d_in[11];
    const float* Wm0    = (const float*)d_in[12];
    const float* Wp0_s  = (const float*)d_in[13];
    const float* Wp0_s2 = (const float*)d_in[14];
    const float* Wp0_v  = (const float*)d_in[15];
    const float* Wr0_sg = (const float*)d_in[16];
    const float* Wr0_v  = (const float*)d_in[17];
    const float* Wr0_s2 = (const float*)d_in[18];
    const float* Wr0_v2 = (const float*)d_in[19];
    const float* W_up1  = (const float*)d_in[20];
    const float* r1_w1  = (const float*)d_in[21];
    const float* r1_w2  = (const float*)d_in[23];
    const float* r1_w3  = (const float*)d_in[25];
    const float* Wm1    = (const float*)d_in[26];
    const float* Wsc1   = (const float*)d_in[27];
    const float* Wp1_s  = (const float*)d_in[28];
    const float* Wp1_s2 = (const float*)d_in[29];
    const float* Wr1_1  = (const float*)d_in[30];
    const float* Wr1_2  = (const float*)d_in[31];
    const float* Wd1    = (const float*)d_in[32];
    const float* bd1    = (const float*)d_in[33];
    const float* a_d    = (const float*)d_in[34];
    const float* Wd2    = (const float*)d_in[35];
    const float* bd2    = (const float*)d_in[36];
    const float* Ws1    = (const float*)d_in[37];
    const float* bs1    = (const float*)d_in[38];
    const float* a_s    = (const float*)d_in[39];
    const float* Ws2    = (const float*)d_in[40];
    const float* bs2    = (const float*)d_in[41];
    float* out = (float*)d_out;

    char* w = (char*)d_ws;
    int*   types = (int*)  (w + OFF_TYPES);
    float* sh    = (float*)(w + OFF_SH);
    float* ef    = (float*)(w + OFF_EF);
    float* hs    = (float*)(w + OFF_HS);
    ushort4* Wb  = (ushort4*)(w + OFF_A);
    float* s0    = (float*)(w + OFF_S0);
    unsigned short* node_b = (unsigned short*)(w + OFF_NODEB);
    int*   cnt   = (int*)  (w + OFF_CNT);
    int*   offs  = (int*)  (w + OFF_OFFS);
    int*   elist = (int*)  (w + OFF_ELIST);
    unsigned short* H_b   = (unsigned short*)(w + OFF_HB);
    float*          Hs    = (float*)(w + OFF_HSC);
    unsigned short* Wd1t  = (unsigned short*)(w + OFF_WD1T);
    unsigned short* Wd2t  = (unsigned short*)(w + OFF_WD2T);
    unsigned short* Ws1t  = (unsigned short*)(w + OFF_WS1T);

    types_kernel<<<(NN + 255)/256, 256, 0, stream>>>(x, types);
    edge_geom<<<(NE + 255)/256, 256, 0, stream>>>(pos, shifts, ei, sh, ef);

    hipMemsetAsync(cnt, 0, (size_t)NN*4, stream);
    deg_kernel<<<(NE + 255)/256, 256, 0, stream>>>(ef, ei, cnt);
    scan_kernel<<<1, 1024, 0, stream>>>(cnt, offs);
    hipMemsetAsync(cnt, 0, (size_t)NN*4, stream);
    fill_kernel<<<(NE + 255)/256, 256, 0, stream>>>(ef, ei, offs, cnt, elist);

    hs_kernel<<<NN/4, 256, 0, stream>>>(W_embed, types, nullptr, W_up0, hs, 0);
    edge_mlp<<<(NE/GE + 3)/4, 256, 0, stream>>>(ef, ei, elist, offs, hs, r0_w1, r0_w2, r0_w3, Wb);
    node_mix0<<<NN/4, 256, 0, stream>>>(Wb, elist, offs, sh, types, Wm0, Wp0_s, Wp0_s2, Wp0_v,
                                        Wr0_sg, Wr0_s2, Wr0_v, Wr0_v2, s0, node_b);

    hs_kernel<<<NN/4, 256, 0, stream>>>(nullptr, nullptr, s0, W_up1, hs, 1);
    edge_mlp<<<(NE/GE + 3)/4, 256, 0, stream>>>(ef, ei, elist, offs, hs, r1_w1, r1_w2, r1_w3, Wb);
    node_mix1<<<NN/4, 256, 0, stream>>>(Wb, elist, offs, sh, types, Wm1, Wp1_s, Wp1_s2, Wsc1,
                                        Wr1_1, Wr1_2, s0, node_b);

    // weight transposes into the now-dead Wbuf region
    wtrans_kernel<<<(400*320 + 255)/256, 256, 0, stream>>>(Wd1, Wd1t, 320, 400, 320);
    wtrans_kernel<<<(1600*416 + 255)/256, 256, 0, stream>>>(Wd2, Wd2t, 400, 1600, 416);
    wtrans_kernel<<<(100*320 + 255)/256, 256, 0, stream>>>(Ws1, Ws1t, 320, 100, 320);

    // readout: node_b @ Wd1 -> H_b (bf16, K padded to 416); H_b @ Wd2 -> out (tanh-dos)
    gemm_mfma<1,1><<<dim3(4, 157), 256, 0, stream>>>(node_b, NIN, Wd1t, 320, bd1, a_d, H_b, 416, NN, 400, 416, 320);
    gemm_mfma<2,0><<<dim3(13, 157), 256, 0, stream>>>(H_b, 416, Wd2t, 416, bd2, a_d, out, NOUT, NN, 1600, 1600, 416);
    gemm_mfma<1,0><<<dim3(1, 157), 256, 0, stream>>>(node_b, NIN, Ws1t, 320, bs1, a_s, Hs, 100, NN, 100, 100, 320);
    scal_kernel<<<(NN*4 + 255)/256, 256, 0, stream>>>(Hs, Ws2, bs2, spd, out);
}